// Round 12
// baseline (183.116 us; speedup 1.0000x reference)
//
#include <hip/hip_runtime.h>
#include <math.h>

#define DIM 256
#define HEADS 8
#define HD 32
// log2(e)/sqrt(32): folded into stored Q so attention uses native exp2
#define QSCALE 0.25504526770295183f

typedef __attribute__((ext_vector_type(8))) short bf16x8;
typedef __attribute__((ext_vector_type(4))) float f32x4;

#if __has_builtin(__builtin_amdgcn_exp2f)
#define EXP2(x) __builtin_amdgcn_exp2f(x)
#else
#define EXP2(x) __expf((x) * 0.6931471805599453f)
#endif

__device__ __forceinline__ unsigned short f2bf(float f) {
  unsigned int u = __float_as_uint(f);
  unsigned int r = u + 0x7fff + ((u >> 16) & 1);   // round-to-nearest-even
  return (unsigned short)(r >> 16);
}
__device__ __forceinline__ float bf2f(unsigned short u) {
  return __uint_as_float(((unsigned int)u) << 16);
}

// MFMA frag layout for a bf16 matrix [R][K] (R%16==0, K%32==0):
//   block id = (r>>4)*(K/32) + (k>>5), 512 shorts per block
//   offset   = ((k&31)>>3)*128 + (r&15)*8 + (k&7)
// GEMM load: base + bid*512 + lane*8  (contiguous 1KB per wave)

// ---------------- prep: avgpools + weight cvts (frag) + zero d_out --------------
__global__ __launch_bounds__(256) void prep_kernel(const float* __restrict__ x,
    const float* __restrict__ pw_w, const float* __restrict__ fus_w,
    float* __restrict__ xs2, float* __restrict__ xs4,
    unsigned short* __restrict__ Wb, unsigned short* __restrict__ Wf,
    float* __restrict__ out) {
  const int gx = blockIdx.x, t = threadIdx.x;
  if (gx < 1024) {                                  // avgpool s=2 -> 256x32x32
    int id = gx * 256 + t;
    int c = id >> 10, n = id & 1023;
    int y = (n >> 5) << 1, x0 = (n & 31) << 1;
    const float* b = x + c * 4096 + y * 64 + x0;
    xs2[id] = (b[0] + b[1] + b[64] + b[65]) * 0.25f;
  } else if (gx < 1280) {                           // avgpool s=4 -> 256x16x16
    int id = (gx - 1024) * 256 + t;
    int c = id >> 8, n = id & 255;
    int y = (n >> 4) << 2, x0 = (n & 15) << 2;
    const float* b = x + c * 4096 + y * 64 + x0;
    float s = 0.f;
    #pragma unroll
    for (int dy = 0; dy < 4; ++dy)
      #pragma unroll
      for (int dx = 0; dx < 4; ++dx) s += b[dy * 64 + dx];
    xs4[id] = s * 0.0625f;
  } else if (gx < 1424) {                           // pw_w -> Wb frag (3x768x256)
    int lid = (gx - 1280) * 256 + t;
    int fb = lid >> 5, l = lid & 31;                // fb < 1152
    int scale = fb / 384, bs = fb - scale * 384;
    int rtile = bs >> 3, kchunk = bs & 7;
    int r = scale * 768 + rtile * 16 + (l & 7) * 2;
    int k = kchunk * 32 + (l >> 3) * 8;
    const float* s0 = pw_w + (size_t)r * 256 + k;
    float4 u0 = *(const float4*)(s0);
    float4 u1 = *(const float4*)(s0 + 4);
    float4 u2 = *(const float4*)(s0 + 256);
    float4 u3 = *(const float4*)(s0 + 260);
    unsigned short* d = Wb + (size_t)fb * 512 + l * 16;
    ushort4 a0 = {f2bf(u0.x), f2bf(u0.y), f2bf(u0.z), f2bf(u0.w)};
    ushort4 a1 = {f2bf(u1.x), f2bf(u1.y), f2bf(u1.z), f2bf(u1.w)};
    ushort4 a2 = {f2bf(u2.x), f2bf(u2.y), f2bf(u2.z), f2bf(u2.w)};
    ushort4 a3 = {f2bf(u3.x), f2bf(u3.y), f2bf(u3.z), f2bf(u3.w)};
    *(ushort4*)(d)      = a0;
    *(ushort4*)(d + 4)  = a1;
    *(ushort4*)(d + 8)  = a2;
    *(ushort4*)(d + 12) = a3;
  } else if (gx < 1472) {                           // fus_w -> Wf frag (256x768)
    int lid = (gx - 1424) * 256 + t;
    int fb = lid >> 5, l = lid & 31;                // fb < 384
    int rtile = fb / 24, kchunk = fb - rtile * 24;
    int r = rtile * 16 + (l & 7) * 2;
    int k = kchunk * 32 + (l >> 3) * 8;
    const float* s0 = fus_w + (size_t)r * 768 + k;
    float4 u0 = *(const float4*)(s0);
    float4 u1 = *(const float4*)(s0 + 4);
    float4 u2 = *(const float4*)(s0 + 768);
    float4 u3 = *(const float4*)(s0 + 772);
    unsigned short* d = Wf + (size_t)fb * 512 + l * 16;
    ushort4 a0 = {f2bf(u0.x), f2bf(u0.y), f2bf(u0.z), f2bf(u0.w)};
    ushort4 a1 = {f2bf(u1.x), f2bf(u1.y), f2bf(u1.z), f2bf(u1.w)};
    ushort4 a2 = {f2bf(u2.x), f2bf(u2.y), f2bf(u2.z), f2bf(u2.w)};
    ushort4 a3 = {f2bf(u3.x), f2bf(u3.y), f2bf(u3.z), f2bf(u3.w)};
    *(ushort4*)(d)      = a0;
    *(ushort4*)(d + 4)  = a1;
    *(ushort4*)(d + 8)  = a2;
    *(ushort4*)(d + 12) = a3;
  } else {                                          // zero d_out (1M floats)
    int id = (gx - 1472) * 256 + t;
    float4 z = {0.f, 0.f, 0.f, 0.f};
    float* p = out + (size_t)id * 16;
    *(float4*)(p)      = z;
    *(float4*)(p + 4)  = z;
    *(float4*)(p + 8)  = z;
    *(float4*)(p + 12) = z;
  }
}

// ---------------- fused dwconv(dw+pos): xdwT FRAG layout, posTc [c][Ns] ---------
// 32c x 32n per block, 1 c-position/thread. 1344 blocks.
__global__ __launch_bounds__(256) void dwt_kernel(const float* __restrict__ x,
    const float* __restrict__ xs2, const float* __restrict__ xs4,
    const float* __restrict__ dw_w, const float* __restrict__ dw_b,
    const float* __restrict__ pos_w, const float* __restrict__ pos_b,
    unsigned short* __restrict__ xdwT, unsigned short* __restrict__ posTc) {
  __shared__ __align__(16) unsigned short lds1[32][40];
  int b = blockIdx.x;
  const float* src;
  int lgHs, wo, soff;
  if (b < 1024)      { src = x;   lgHs = 6; wo = 0; soff = 0; }
  else if (b < 1280) { b -= 1024; src = xs2; lgHs = 5; wo = 1; soff = 1048576; }
  else               { b -= 1280; src = xs4; lgHs = 4; wo = 2; soff = 1310720; }
  const int c0 = (b & 7) * 32;
  const int n0 = (b >> 3) * 32;
  const int Hs = 1 << lgHs;
  const int Ns = Hs * Hs;
  const int t = threadIdx.x;
  const int cl = t >> 3;
  const int c = c0 + cl;
  const int nb = (t & 7) * 4;
  const float* w1 = dw_w + wo * 2304 + c * 9;
  const float* w2 = pos_w + wo * 2304 + c * 9;
  const float b1 = dw_b[wo * 256 + c], b2 = pos_b[wo * 256 + c];
  const int gn = n0 + nb;
  const int y = gn >> lgHs, xg = gn & (Hs - 1);
  const float* sc = src + c * Ns;
  float r[3][6];
  #pragma unroll
  for (int ky = 0; ky < 3; ++ky) {
    int yy = y + ky - 1;
    bool rok = (yy >= 0) && (yy < Hs);
    #pragma unroll
    for (int j = 0; j < 6; ++j) {
      int xx = xg - 1 + j;
      r[ky][j] = (rok && xx >= 0 && xx < Hs) ? sc[yy * Hs + xx] : 0.f;
    }
  }
  ushort4 pst;
  unsigned short* ps = (unsigned short*)&pst;
  #pragma unroll
  for (int i = 0; i < 4; ++i) {
    float s1 = b1, s2 = b2;
    #pragma unroll
    for (int ky = 0; ky < 3; ++ky)
      #pragma unroll
      for (int kx = 0; kx < 3; ++kx) {
        float v = r[ky][i + kx];
        s1 += v * w1[ky * 3 + kx];
        s2 += v * w2[ky * 3 + kx];
      }
    lds1[nb + i][cl] = f2bf(s1);
    ps[i] = f2bf(s2);
  }
  *(ushort4*)(posTc + soff + (size_t)c * Ns + gn) = pst;
  __syncthreads();
  if (t < 128) {                                    // 2 frag blocks x 512 shorts
    int blk = t >> 6, l = t & 63;
    size_t bid = (size_t)((n0 >> 4) + blk) * 8 + (c0 >> 5);
    *(bf16x8*)(xdwT + soff + bid * 512 + (size_t)l * 8) =
        *(const bf16x8*)&lds1[blk * 16 + (l & 15)][(l >> 4) * 8];
  }
}

// ---------------- QKV GEMM, frag loads -> frag outputs; posTc coalesced ---------
__global__ __launch_bounds__(256) void gemm_qkv_all(const unsigned short* __restrict__ WbA,
    const unsigned short* __restrict__ xdwTA, const float* __restrict__ biasA,
    const unsigned short* __restrict__ posTA, unsigned short* __restrict__ Qf,
    unsigned short* __restrict__ Kf, unsigned short* __restrict__ Vf) {
  int by = blockIdx.y;
  int Ns, off;
  const unsigned short *Wb, *xdwT, *posT;
  const float* bias;
  if (by < 64) {
    Ns = 4096; off = 0;
    Wb = WbA; bias = biasA;
  } else if (by < 80) {
    Ns = 1024; off = 1048576; by -= 64;
    Wb = WbA + 196608; bias = biasA + 768;
  } else {
    Ns = 256; off = 1310720; by -= 80;
    Wb = WbA + 393216; bias = biasA + 1536;
  }
  xdwT = xdwTA + off; posT = posTA + off;
  const int t = threadIdx.x;
  const int wave = t >> 6, lane = t & 63;
  const int ln = lane & 15, quad = lane >> 4;
  const int o0 = blockIdx.x * 64 + (wave & 1) * 32;
  const int n0 = by * 64 + (wave >> 1) * 32;
  const int at0 = (o0 >> 4) * 8, at1 = at0 + 8;
  const int bt0 = (n0 >> 4) * 8, bt1 = bt0 + 8;
  const bool vblk = blockIdx.x >= 8;
  f32x4 acc[2][2] = {};
  if (!vblk) {
    #pragma unroll
    for (int ks = 0; ks < 8; ++ks) {
      bf16x8 af0 = *(const bf16x8*)(Wb + (size_t)(at0 + ks) * 512 + lane * 8);
      bf16x8 af1 = *(const bf16x8*)(Wb + (size_t)(at1 + ks) * 512 + lane * 8);
      bf16x8 bv0 = *(const bf16x8*)(xdwT + (size_t)(bt0 + ks) * 512 + lane * 8);
      bf16x8 bv1 = *(const bf16x8*)(xdwT + (size_t)(bt1 + ks) * 512 + lane * 8);
      acc[0][0] = __builtin_amdgcn_mfma_f32_16x16x32_bf16(af0, bv0, acc[0][0], 0, 0, 0);
      acc[0][1] = __builtin_amdgcn_mfma_f32_16x16x32_bf16(af0, bv1, acc[0][1], 0, 0, 0);
      acc[1][0] = __builtin_amdgcn_mfma_f32_16x16x32_bf16(af1, bv0, acc[1][0], 0, 0, 0);
      acc[1][1] = __builtin_amdgcn_mfma_f32_16x16x32_bf16(af1, bv1, acc[1][1], 0, 0, 0);
    }
  } else {
    #pragma unroll
    for (int ks = 0; ks < 8; ++ks) {
      bf16x8 af0 = *(const bf16x8*)(Wb + (size_t)(at0 + ks) * 512 + lane * 8);
      bf16x8 af1 = *(const bf16x8*)(Wb + (size_t)(at1 + ks) * 512 + lane * 8);
      bf16x8 bv0 = *(const bf16x8*)(xdwT + (size_t)(bt0 + ks) * 512 + lane * 8);
      bf16x8 bv1 = *(const bf16x8*)(xdwT + (size_t)(bt1 + ks) * 512 + lane * 8);
      // swapped: C^T -> row = n, col = o
      acc[0][0] = __builtin_amdgcn_mfma_f32_16x16x32_bf16(bv0, af0, acc[0][0], 0, 0, 0);
      acc[0][1] = __builtin_amdgcn_mfma_f32_16x16x32_bf16(bv0, af1, acc[0][1], 0, 0, 0);
      acc[1][0] = __builtin_amdgcn_mfma_f32_16x16x32_bf16(bv1, af0, acc[1][0], 0, 0, 0);
      acc[1][1] = __builtin_amdgcn_mfma_f32_16x16x32_bf16(bv1, af1, acc[1][1], 0, 0, 0);
    }
  }
  if (!vblk) {                                      // q or k: rows=o, cols=n
    const int cat = blockIdx.x >> 2;                // 0=q, 1=k
    #pragma unroll
    for (int mt = 0; mt < 2; ++mt) {
      int ot = o0 + mt * 16 + quad * 4;
      float bs0 = bias[ot], bs1 = bias[ot + 1], bs2 = bias[ot + 2], bs3 = bias[ot + 3];
      int cb = ot & 255;
      #pragma unroll
      for (int nt = 0; nt < 2; ++nt) {
        int nn = n0 + nt * 16 + ln;
        f32x4 v = acc[mt][nt];
        const unsigned short* pp = posT + (size_t)cb * Ns + nn;
        v.x += bs0 + bf2f(pp[0]);
        v.y += bs1 + bf2f(pp[Ns]);
        v.z += bs2 + bf2f(pp[2 * Ns]);
        v.w += bs3 + bf2f(pp[3 * Ns]);
        if (cat == 0) { v.x *= QSCALE; v.y *= QSCALE; v.z *= QSCALE; v.w *= QSCALE; }
        ushort4 st;
        st.x = f2bf(v.x); st.y = f2bf(v.y); st.z = f2bf(v.z); st.w = f2bf(v.w);
        int hh = cb >> 5, d = cb & 31;
        unsigned short* dst = (cat == 0 ? Qf : Kf) + off;
        size_t a = ((size_t)(hh * (Ns >> 4) + (nn >> 4)) * 64 + (d >> 3) * 16 + (nn & 15)) * 8
                   + (d & 7);
        *(ushort4*)(dst + a) = st;
      }
    }
  } else {                                          // v: rows=n, cols=o
    #pragma unroll
    for (int a = 0; a < 2; ++a) {
      int nbase = n0 + a * 16 + quad * 4;
      #pragma unroll
      for (int bb = 0; bb < 2; ++bb) {
        int o = o0 + bb * 16 + ln;
        int c = o - 512;
        int hh = c >> 5, d = c & 31;
        int dt = d >> 4, dl = d & 15;
        float bs = bias[o];
        f32x4 v = acc[a][bb];
        ushort4 st;
        st.x = f2bf(v.x + bs); st.y = f2bf(v.y + bs);
        st.z = f2bf(v.z + bs); st.w = f2bf(v.w + bs);
        size_t adr = ((((size_t)hh * (Ns >> 5) + (nbase >> 5)) * 2 + dt) * 64
                      + ((nbase & 31) >> 3) * 16 + dl) * 8 + (nbase & 7);
        *(ushort4*)(Vf + off + adr) = st;
      }
    }
  }
}

// ---------------- attention: fragment-layout direct loads + MFMA row-sums -------
// z 0..7: s1 splits; z 8..15: s2 splits (x<8); z 16..19: s4 splits (x<2).
__global__ __launch_bounds__(256) void attn_all_kernel(
    const unsigned short* __restrict__ Qf, const unsigned short* __restrict__ Kf,
    const unsigned short* __restrict__ Vf,
    unsigned short* __restrict__ accp1, unsigned short* __restrict__ p2,
    unsigned short* __restrict__ p4, float* __restrict__ ls1,
    float* __restrict__ ls2, float* __restrict__ ls4) {
  __shared__ unsigned short pt_lds[4 * 32 * 72];    // wave-private P^T [n][m], pad 72
  const int z = blockIdx.z;
  unsigned short* accp;
  float* lsump;
  int Ns, lgMs, sp, off;
  if (z < 8) {
    accp = accp1; lsump = ls1; Ns = 4096; lgMs = 9; sp = z; off = 0;
  } else if (z < 16) {
    if (blockIdx.x >= 8) return;
    accp = p2; lsump = ls2; Ns = 1024; lgMs = 7; sp = z - 8; off = 1048576;
  } else {
    if (blockIdx.x >= 2) return;
    accp = p4; lsump = ls4; Ns = 256; lgMs = 6; sp = z - 16; off = 1310720;
  }
  const int t = threadIdx.x;
  const int wave = t >> 6, lane = t & 63;
  const int ln = lane & 15, quad = lane >> 4;
  const int h = blockIdx.y;
  const int n0 = blockIdx.x * 128 + wave * 32;
  const unsigned short* qp = Qf + off
      + ((size_t)(h * (Ns >> 4) + (n0 >> 4)) * 64 + lane) * 8;
  bf16x8 qf0 = *(const bf16x8*)(qp);
  bf16x8 qf1 = *(const bf16x8*)(qp + 512);
  unsigned short* ptw = pt_lds + wave * (32 * 72);
  f32x4 acc[2][2] = {};
  f32x4 acc_l0 = {0.f, 0.f, 0.f, 0.f}, acc_l1 = {0.f, 0.f, 0.f, 0.f};
  const f32x4 zero = {0.f, 0.f, 0.f, 0.f};
  const short kOne = (short)0x3F80;                 // bf16 1.0
  const bf16x8 onesf = {kOne, kOne, kOne, kOne, kOne, kOne, kOne, kOne};
  const int m0s = sp << lgMs;
  const int nch = 1 << (lgMs - 6);
  const unsigned short* kp = Kf + off
      + ((size_t)(h * (Ns >> 4) + (m0s >> 4)) * 64 + lane) * 8;
  const unsigned short* vp = Vf + off
      + (((size_t)h * (Ns >> 5) + (m0s >> 5)) * 128 + lane) * 8;
  for (int ch = 0; ch < nch; ++ch) {
    const unsigned short* kc = kp + ch * 2048;
    const unsigned short* vc = vp + ch * 2048;
    bf16x8 kf0 = *(const bf16x8*)(kc);
    bf16x8 kf1 = *(const bf16x8*)(kc + 512);
    bf16x8 kf2 = *(const bf16x8*)(kc + 1024);
    bf16x8 kf3 = *(const bf16x8*)(kc + 1536);
    bf16x8 vf00 = *(const bf16x8*)(vc);          // ks0, dt0
    bf16x8 vf10 = *(const bf16x8*)(vc + 512);    // ks0, dt1
    bf16x8 vf01 = *(const bf16x8*)(vc + 1024);   // ks1, dt0
    bf16x8 vf11 = *(const bf16x8*)(vc + 1536);   // ks1, dt1
    f32x4 s[4][2];
    s[0][0] = __builtin_amdgcn_mfma_f32_16x16x32_bf16(kf0, qf0, zero, 0, 0, 0);
    s[0][1] = __builtin_amdgcn_mfma_f32_16x16x32_bf16(kf0, qf1, zero, 0, 0, 0);
    s[1][0] = __builtin_amdgcn_mfma_f32_16x16x32_bf16(kf1, qf0, zero, 0, 0, 0);
    s[1][1] = __builtin_amdgcn_mfma_f32_16x16x32_bf16(kf1, qf1, zero, 0, 0, 0);
    s[2][0] = __builtin_amdgcn_mfma_f32_16x16x32_bf16(kf2, qf0, zero, 0, 0, 0);
    s[2][1] = __builtin_amdgcn_mfma_f32_16x16x32_bf16(kf2, qf1, zero, 0, 0, 0);
    s[3][0] = __builtin_amdgcn_mfma_f32_16x16x32_bf16(kf3, qf0, zero, 0, 0, 0);
    s[3][1] = __builtin_amdgcn_mfma_f32_16x16x32_bf16(kf3, qf1, zero, 0, 0, 0);
    #pragma unroll
    for (int mt = 0; mt < 4; ++mt) {
      #pragma unroll
      for (int nt = 0; nt < 2; ++nt) {
        float e0 = EXP2(s[mt][nt].x);
        float e1 = EXP2(s[mt][nt].y);
        float e2 = EXP2(s[mt][nt].z);
        float e3 = EXP2(s[mt][nt].w);
        uint2 pk;                                   // bf16-truncate pack, 1 op/pair
        pk.x = __builtin_amdgcn_perm(__float_as_uint(e1), __float_as_uint(e0), 0x07060302);
        pk.y = __builtin_amdgcn_perm(__float_as_uint(e3), __float_as_uint(e2), 0x07060302);
        *(uint2*)&ptw[(nt * 16 + ln) * 72 + mt * 16 + quad * 4] = pk;
      }
    }
    #pragma unroll
    for (int ks = 0; ks < 2; ++ks) {
      bf16x8 pf0 = *(const bf16x8*)&ptw[ln * 72 + ks * 32 + quad * 8];
      bf16x8 pf1 = *(const bf16x8*)&ptw[(16 + ln) * 72 + ks * 32 + quad * 8];
      bf16x8 va = ks ? vf01 : vf00;
      bf16x8 vbf = ks ? vf11 : vf10;
      acc[0][0] = __builtin_amdgcn_mfma_f32_16x16x32_bf16(va, pf0, acc[0][0], 0, 0, 0);
      acc[0][1] = __builtin_amdgcn_mfma_f32_16x16x32_bf16(va, pf1, acc[0][1], 0, 0, 0);
      acc[1][0] = __builtin_amdgcn_mfma_f32_16x16x32_bf16(vbf, pf0, acc[1][0], 0, 0, 0);
      acc[1][1] = __builtin_amdgcn_mfma_f32_16x16x32_bf16(vbf, pf1, acc[1][1], 0, 0, 0);
      acc_l0 = __builtin_amdgcn_mfma_f32_16x16x32_bf16(onesf, pf0, acc_l0, 0, 0, 0);
      acc_l1 = __builtin_amdgcn_mfma_f32_16x16x32_bf16(onesf, pf1, acc_l1, 0, 0, 0);
    }
  }
  unsigned short* ap = accp + ((size_t)sp * 256 + h * 32) * Ns;
  #pragma unroll
  for (int dt = 0; dt < 2; ++dt) {
    #pragma unroll
    for (int r = 0; r < 4; ++r) {
      int cl = dt * 16 + quad * 4 + r;
      ap[(size_t)cl * Ns + n0 + ln]      = f2bf(((const float*)&acc[dt][0])[r]);
      ap[(size_t)cl * Ns + n0 + 16 + ln] = f2bf(((const float*)&acc[dt][1])[r]);
    }
  }
  if (lane < 16) {
    float* lp = lsump + ((size_t)sp * 8 + h) * Ns + n0;
    lp[lane]      = acc_l0.x;                       // all rows of ones-MFMA equal lsum_n
    lp[16 + lane] = acc_l1.x;
  }
}

// ---------------- combine s2 (8 splits) + s4 (4 splits) in one launch -----------
__global__ __launch_bounds__(256) void combine24_kernel(const unsigned short* __restrict__ p2,
    const float* __restrict__ ls2, const unsigned short* __restrict__ p4,
    const float* __restrict__ ls4, float* __restrict__ out2, float* __restrict__ out4) {
  int id = blockIdx.x * 256 + threadIdx.x;
  if (id < 262144) {                                // s2: 256 x 1024
    int n = id & 1023, h = id >> 15;
    float v = 0.f, d = 0.f;
    #pragma unroll
    for (int sp = 0; sp < 8; ++sp) {
      v += bf2f(p2[sp * 262144 + id]);
      d += ls2[sp * 8192 + h * 1024 + n];
    }
    out2[id] = v / d;
  } else {                                          // s4: 256 x 256
    int idl = id - 262144;
    int n = idl & 255, h = idl >> 13;
    float v = 0.f, d = 0.f;
    #pragma unroll
    for (int sp = 0; sp < 4; ++sp) {
      v += bf2f(p4[sp * 65536 + idl]);
      d += ls4[sp * 2048 + h * 256 + n];
    }
    out4[idl] = v / d;
  }
}

// ---------------- build catT in FRAG layout (R=4096 rows n, K=768 cols c) -------
__global__ __launch_bounds__(256) void build_catT_kernel(const unsigned short* __restrict__ accp,
    const float* __restrict__ lsum1, const float* __restrict__ out2,
    const float* __restrict__ out4, unsigned short* __restrict__ catT) {
  __shared__ unsigned short lds[64][72];
  const int t = threadIdx.x;
  const int n0 = blockIdx.x * 64;
  const int by = blockIdx.y;
  const int c0 = by * 64;
  if (by < 4) {
    #pragma unroll
    for (int p = 0; p < 4; ++p) {
      int ct = p * 16 + (t >> 4);
      int c = c0 + ct;
      int h = c >> 5;
      int nn = (t & 15) * 4;
      float vs[4] = {0.f, 0.f, 0.f, 0.f};
      float ds[4] = {0.f, 0.f, 0.f, 0.f};
      #pragma unroll
      for (int sp = 0; sp < 8; ++sp) {
        ushort4 a = *(const ushort4*)(accp + (size_t)sp * 1048576 + (size_t)c * 4096 + n0 + nn);
        vs[0] += bf2f(a.x); vs[1] += bf2f(a.y); vs[2] += bf2f(a.z); vs[3] += bf2f(a.w);
        float4 dd = *(const float4*)(lsum1 + (size_t)sp * 32768 + (size_t)h * 4096 + n0 + nn);
        ds[0] += dd.x; ds[1] += dd.y; ds[2] += dd.z; ds[3] += dd.w;
      }
      lds[nn + 0][ct] = f2bf(vs[0] / ds[0]);
      lds[nn + 1][ct] = f2bf(vs[1] / ds[1]);
      lds[nn + 2][ct] = f2bf(vs[2] / ds[2]);
      lds[nn + 3][ct] = f2bf(vs[3] / ds[3]);
    }
  } else {
    const bool s2 = by < 8;
    const float* src = s2 ? out2 : out4;
    const int Hs = s2 ? 32 : 16;
    const int coff = s2 ? 256 : 512;
    const float sc = (float)Hs / 64.0f;
    #pragma unroll
    for (int p = 0; p < 4; ++p) {
      int ct = p * 16 + (t >> 4);
      const float* s = src + (size_t)(c0 - coff + ct) * Hs * Hs;
      int nn = (t & 15) * 4;
      #pragma unroll
      for (int i = 0; i < 4; ++i) {
        int n = n0 + nn + i;
        int y = n >> 6, x = n & 63;
        float fy = ((float)y + 0.5f) * sc - 0.5f;
        float fx = ((float)x + 0.5f) * sc - 0.5f;
        float fy0 = floorf(fy), fx0 = floorf(fx);
        int y0 = (int)fy0, x0 = (int)fx0;
        float ty = fy - fy0, tx = fx - fx0;
        int y0c = min(max(y0, 0), Hs - 1), y1c = min(max(y0 + 1, 0), Hs - 1);
        int x0c = min(max(x0, 0), Hs - 1), x1c = min(max(x0 + 1, 0), Hs - 1);
        float v00 = s[y0c * Hs + x0c], v01 = s[y0c * Hs + x1c];
        float v10 = s[y1c * Hs + x0c], v11 = s[y1c * Hs + x1c];
        float v0 = v00 + (v01 - v00) * tx;
        float v1 = v10 + (v11 - v10) * tx;
        lds[nn + i][ct] = f2bf(v0 + (v1 - v0) * ty);
      }
    }
  }
  __syncthreads();
  // frag write: 8 blocks (4 n-tiles x 2 c-chunks) x 512 shorts, 32 threads each
  int blk = t >> 5, l = t & 31;
  int ntile = blk >> 1, cchunk = blk & 1;
  int koct = l >> 3, r1 = (l & 7) * 2;
  size_t bid = (size_t)((n0 >> 4) + ntile) * 24 + (c0 >> 5) + cchunk;
  unsigned short* dst = catT + bid * 512 + (size_t)l * 16;
  *(bf16x8*)(dst)     = *(const bf16x8*)&lds[ntile * 16 + r1][cchunk * 32 + koct * 8];
  *(bf16x8*)(dst + 8) = *(const bf16x8*)&lds[ntile * 16 + r1 + 1][cchunk * 32 + koct * 8];
}

// ---------------- fusion GEMM: frag loads, swapped operands, atomic output ------
// out was zeroed by prep; sp==0 folds bias. All splits atomicAdd (order-free).
__global__ __launch_bounds__(256) void gemm_fus_mfma(const unsigned short* __restrict__ Wf,
    const unsigned short* __restrict__ catT, const float* __restrict__ bias,
    float* __restrict__ out) {
  const int t = threadIdx.x;
  const int wave = t >> 6, lane = t & 63;
  const int ln = lane & 15, quad = lane >> 4;
  const int o0 = blockIdx.x * 64 + (wave & 1) * 32;
  const int n0 = blockIdx.y * 64 + (wave >> 1) * 32;
  const int sp = blockIdx.z;
  const int at0 = (o0 >> 4) * 24 + sp * 8, at1 = at0 + 24;
  const int bt0 = (n0 >> 4) * 24 + sp * 8, bt1 = bt0 + 24;
  f32x4 acc[2][2] = {};                             // [n-tile][o-tile] (C^T)
  #pragma unroll
  for (int ks = 0; ks < 8; ++ks) {
    bf16x8 af0 = *(const bf16x8*)(Wf + (size_t)(at0 + ks) * 512 + lane * 8);
    bf16x8 af1 = *(const bf16x8*)(Wf + (size_t)(at1 + ks) * 512 + lane * 8);
    bf16x8 bv0 = *(const bf16x8*)(catT + (size_t)(bt0 + ks) * 512 + lane * 8);
    bf16x8 bv1 = *(const bf16x8*)(catT + (size_t)(bt1 + ks) * 512 + lane * 8);
    acc[0][0] = __builtin_amdgcn_mfma_f32_16x16x32_bf16(bv0, af0, acc[0][0], 0, 0, 0);
    acc[0][1] = __builtin_amdgcn_mfma_f32_16x16x32_bf16(bv0, af1, acc[0][1], 0, 0, 0);
    acc[1][0] = __builtin_amdgcn_mfma_f32_16x16x32_bf16(bv1, af0, acc[1][0], 0, 0, 0);
    acc[1][1] = __builtin_amdgcn_mfma_f32_16x16x32_bf16(bv1, af1, acc[1][1], 0, 0, 0);
  }
  #pragma unroll
  for (int a = 0; a < 2; ++a) {
    int nbase = n0 + a * 16 + quad * 4;
    #pragma unroll
    for (int bb = 0; bb < 2; ++bb) {
      int o = o0 + bb * 16 + ln;
      float badd = (sp == 0) ? bias[o] : 0.f;
      float* po = out + (size_t)o * 4096 + nbase;
      atomicAdd(po + 0, acc[a][bb].x + badd);
      atomicAdd(po + 1, acc[a][bb].y + badd);
      atomicAdd(po + 2, acc[a][bb].z + badd);
      atomicAdd(po + 3, acc[a][bb].w + badd);
    }
  }
}

extern "C" void kernel_launch(void* const* d_in, const int* in_sizes, int n_in,
                              void* d_out, int out_size, void* d_ws, size_t ws_size,
                              hipStream_t stream) {
  const float* x     = (const float*)d_in[0];
  const float* dw_w  = (const float*)d_in[1];
  const float* dw_b  = (const float*)d_in[2];
  const float* pw_w  = (const float*)d_in[3];
  const float* pw_b  = (const float*)d_in[4];
  const float* pos_w = (const float*)d_in[5];
  const float* pos_b = (const float*)d_in[6];
  const float* fus_w = (const float*)d_in[7];
  const float* fus_b = (const float*)d_in[8];
  float* out = (float*)d_out;
  float* ws = (float*)d_ws;

  // ws layout (floats), total 12,058,624 fl = 46.0 MB (aliasing noted inline)
  float* scratch = ws;                       // 1,376,256  [attn s2/s4 bf16 partials]
  float* posF   = ws + 1376256;              // 1,376,256  [lsum1/2/4 + out2/out4]
  float* accpF  = ws + 2752512;              // 4,194,304  [xs2/xs4 early; s1 bf16 partials]
  unsigned short* xdwT = (unsigned short*)(ws + 6946816);   // 1,376,256 us (frag)
  unsigned short* posTc = (unsigned short*)(ws + 7634944);  // 1,376,256 us ([c][Ns])
  unsigned short* Qf   = (unsigned short*)(ws + 8323072);   // 1,376,256 us
  unsigned short* Kf   = Qf + 1376256;                      // 1,376,256 us
  unsigned short* Vf   = (unsigned short*)(ws + 9699328);   // 1,376,256 us
  unsigned short* catT = (unsigned short*)(ws + 10387456);  // 3,145,728 us [Wb early]
  unsigned short* Wf   = (unsigned short*)(ws + 11960320);  //   196,608 us

  float* xs2 = accpF;                        // dead before attn-s1 writes accp
  float* xs4 = accpF + 262144;
  unsigned short* Wb = catT;                 // dead before build_catT writes catT
  unsigned short* accp = (unsigned short*)accpF;            // 8,388,608 us (8 splits)
  float* lsump1 = posF;                      // 262,144 (8sp x 8h x 4096)
  float* lsump2 = posF + 262144;             // 65,536
  float* lsump4 = posF + 327680;             // 8,192
  float* out2   = posF + 335872;             // 262,144
  float* out4   = posF + 598016;             // 65,536
  unsigned short* p2 = (unsigned short*)scratch;            // 2,097,152 us (8 splits)
  unsigned short* p4 = (unsigned short*)scratch + 2097152;  //   262,144 us (4 splits)

  prep_kernel<<<1728, 256, 0, stream>>>(x, pw_w, fus_w, xs2, xs4, Wb, Wf, out);
  dwt_kernel<<<1344, 256, 0, stream>>>(x, xs2, xs4, dw_w, dw_b, pos_w, pos_b, xdwT, posTc);
  gemm_qkv_all<<<dim3(12, 84), 256, 0, stream>>>(Wb, xdwT, pw_b, posTc, Qf, Kf, Vf);

  attn_all_kernel<<<dim3(32, 8, 20), 256, 0, stream>>>(Qf, Kf, Vf, accp, p2, p4,
                                                       lsump1, lsump2, lsump4);
  combine24_kernel<<<1280, 256, 0, stream>>>(p2, lsump2, p4, lsump4, out2, out4);

  build_catT_kernel<<<dim3(64, 12), 256, 0, stream>>>(accp, lsump1, out2, out4, catT);
  gemm_fus_mfma<<<dim3(4, 64, 3), 256, 0, stream>>>(Wf, catT, fus_b, out);
}

// Round 13
// 148.183 us; speedup vs baseline: 1.2357x; 1.2357x over previous
//
#include <hip/hip_runtime.h>
#include <math.h>

#define DIM 256
#define HEADS 8
#define HD 32
// log2(e)/sqrt(32): folded into stored Q so attention uses native exp2
#define QSCALE 0.25504526770295183f

typedef __attribute__((ext_vector_type(8))) short bf16x8;
typedef __attribute__((ext_vector_type(4))) float f32x4;

#if __has_builtin(__builtin_amdgcn_exp2f)
#define EXP2(x) __builtin_amdgcn_exp2f(x)
#else
#define EXP2(x) __expf((x) * 0.6931471805599453f)
#endif

__device__ __forceinline__ unsigned short f2bf(float f) {
  unsigned int u = __float_as_uint(f);
  unsigned int r = u + 0x7fff + ((u >> 16) & 1);   // round-to-nearest-even
  return (unsigned short)(r >> 16);
}
__device__ __forceinline__ float bf2f(unsigned short u) {
  return __uint_as_float(((unsigned int)u) << 16);
}

// MFMA frag layout for a bf16 matrix [R][K] (R%16==0, K%32==0):
//   block id = (r>>4)*(K/32) + (k>>5), 512 shorts per block
//   offset   = ((k&31)>>3)*128 + (r&15)*8 + (k&7)
// GEMM load: base + bid*512 + lane*8  (contiguous 1KB per wave)

// ---------------- prep: avgpools + weight cvts into FRAG layout -----------------
__global__ __launch_bounds__(256) void prep_kernel(const float* __restrict__ x,
    const float* __restrict__ pw_w, const float* __restrict__ fus_w,
    float* __restrict__ xs2, float* __restrict__ xs4,
    unsigned short* __restrict__ Wb, unsigned short* __restrict__ Wf) {
  const int gx = blockIdx.x, t = threadIdx.x;
  if (gx < 1024) {                                  // avgpool s=2 -> 256x32x32
    int id = gx * 256 + t;
    int c = id >> 10, n = id & 1023;
    int y = (n >> 5) << 1, x0 = (n & 31) << 1;
    const float* b = x + c * 4096 + y * 64 + x0;
    xs2[id] = (b[0] + b[1] + b[64] + b[65]) * 0.25f;
  } else if (gx < 1280) {                           // avgpool s=4 -> 256x16x16
    int id = (gx - 1024) * 256 + t;
    int c = id >> 8, n = id & 255;
    int y = (n >> 4) << 2, x0 = (n & 15) << 2;
    const float* b = x + c * 4096 + y * 64 + x0;
    float s = 0.f;
    #pragma unroll
    for (int dy = 0; dy < 4; ++dy)
      #pragma unroll
      for (int dx = 0; dx < 4; ++dx) s += b[dy * 64 + dx];
    xs4[id] = s * 0.0625f;
  } else if (gx < 1424) {                           // pw_w -> Wb frag (3x768x256)
    int lid = (gx - 1280) * 256 + t;
    int fb = lid >> 5, l = lid & 31;                // fb < 1152
    int scale = fb / 384, bs = fb - scale * 384;
    int rtile = bs >> 3, kchunk = bs & 7;
    int r = scale * 768 + rtile * 16 + (l & 7) * 2;
    int k = kchunk * 32 + (l >> 3) * 8;
    const float* s0 = pw_w + (size_t)r * 256 + k;
    float4 u0 = *(const float4*)(s0);
    float4 u1 = *(const float4*)(s0 + 4);
    float4 u2 = *(const float4*)(s0 + 256);
    float4 u3 = *(const float4*)(s0 + 260);
    unsigned short* d = Wb + (size_t)fb * 512 + l * 16;
    ushort4 a0 = {f2bf(u0.x), f2bf(u0.y), f2bf(u0.z), f2bf(u0.w)};
    ushort4 a1 = {f2bf(u1.x), f2bf(u1.y), f2bf(u1.z), f2bf(u1.w)};
    ushort4 a2 = {f2bf(u2.x), f2bf(u2.y), f2bf(u2.z), f2bf(u2.w)};
    ushort4 a3 = {f2bf(u3.x), f2bf(u3.y), f2bf(u3.z), f2bf(u3.w)};
    *(ushort4*)(d)      = a0;
    *(ushort4*)(d + 4)  = a1;
    *(ushort4*)(d + 8)  = a2;
    *(ushort4*)(d + 12) = a3;
  } else {                                          // fus_w -> Wf frag (256x768)
    int lid = (gx - 1424) * 256 + t;
    int fb = lid >> 5, l = lid & 31;                // fb < 384
    int rtile = fb / 24, kchunk = fb - rtile * 24;
    int r = rtile * 16 + (l & 7) * 2;
    int k = kchunk * 32 + (l >> 3) * 8;
    const float* s0 = fus_w + (size_t)r * 768 + k;
    float4 u0 = *(const float4*)(s0);
    float4 u1 = *(const float4*)(s0 + 4);
    float4 u2 = *(const float4*)(s0 + 768);
    float4 u3 = *(const float4*)(s0 + 772);
    unsigned short* d = Wf + (size_t)fb * 512 + l * 16;
    ushort4 a0 = {f2bf(u0.x), f2bf(u0.y), f2bf(u0.z), f2bf(u0.w)};
    ushort4 a1 = {f2bf(u1.x), f2bf(u1.y), f2bf(u1.z), f2bf(u1.w)};
    ushort4 a2 = {f2bf(u2.x), f2bf(u2.y), f2bf(u2.z), f2bf(u2.w)};
    ushort4 a3 = {f2bf(u3.x), f2bf(u3.y), f2bf(u3.z), f2bf(u3.w)};
    *(ushort4*)(d)      = a0;
    *(ushort4*)(d + 4)  = a1;
    *(ushort4*)(d + 8)  = a2;
    *(ushort4*)(d + 12) = a3;
  }
}

// ---------------- fused dwconv(dw+pos): xdwT FRAG layout, posTc [c][Ns] ---------
// 32c x 32n per block, 1 c-position/thread. 1344 blocks.
__global__ __launch_bounds__(256) void dwt_kernel(const float* __restrict__ x,
    const float* __restrict__ xs2, const float* __restrict__ xs4,
    const float* __restrict__ dw_w, const float* __restrict__ dw_b,
    const float* __restrict__ pos_w, const float* __restrict__ pos_b,
    unsigned short* __restrict__ xdwT, unsigned short* __restrict__ posTc) {
  __shared__ __align__(16) unsigned short lds1[32][40];
  int b = blockIdx.x;
  const float* src;
  int lgHs, wo, soff;
  if (b < 1024)      { src = x;   lgHs = 6; wo = 0; soff = 0; }
  else if (b < 1280) { b -= 1024; src = xs2; lgHs = 5; wo = 1; soff = 1048576; }
  else               { b -= 1280; src = xs4; lgHs = 4; wo = 2; soff = 1310720; }
  const int c0 = (b & 7) * 32;
  const int n0 = (b >> 3) * 32;
  const int Hs = 1 << lgHs;
  const int Ns = Hs * Hs;
  const int t = threadIdx.x;
  const int cl = t >> 3;
  const int c = c0 + cl;
  const int nb = (t & 7) * 4;
  const float* w1 = dw_w + wo * 2304 + c * 9;
  const float* w2 = pos_w + wo * 2304 + c * 9;
  const float b1 = dw_b[wo * 256 + c], b2 = pos_b[wo * 256 + c];
  const int gn = n0 + nb;
  const int y = gn >> lgHs, xg = gn & (Hs - 1);
  const float* sc = src + c * Ns;
  float r[3][6];
  #pragma unroll
  for (int ky = 0; ky < 3; ++ky) {
    int yy = y + ky - 1;
    bool rok = (yy >= 0) && (yy < Hs);
    #pragma unroll
    for (int j = 0; j < 6; ++j) {
      int xx = xg - 1 + j;
      r[ky][j] = (rok && xx >= 0 && xx < Hs) ? sc[yy * Hs + xx] : 0.f;
    }
  }
  ushort4 pst;
  unsigned short* ps = (unsigned short*)&pst;
  #pragma unroll
  for (int i = 0; i < 4; ++i) {
    float s1 = b1, s2 = b2;
    #pragma unroll
    for (int ky = 0; ky < 3; ++ky)
      #pragma unroll
      for (int kx = 0; kx < 3; ++kx) {
        float v = r[ky][i + kx];
        s1 += v * w1[ky * 3 + kx];
        s2 += v * w2[ky * 3 + kx];
      }
    lds1[nb + i][cl] = f2bf(s1);
    ps[i] = f2bf(s2);
  }
  *(ushort4*)(posTc + soff + (size_t)c * Ns + gn) = pst;
  __syncthreads();
  if (t < 128) {                                    // 2 frag blocks x 512 shorts
    int blk = t >> 6, l = t & 63;
    size_t bid = (size_t)((n0 >> 4) + blk) * 8 + (c0 >> 5);
    *(bf16x8*)(xdwT + soff + bid * 512 + (size_t)l * 8) =
        *(const bf16x8*)&lds1[blk * 16 + (l & 15)][(l >> 4) * 8];
  }
}

// ---------------- QKV GEMM, frag loads -> frag outputs; posTc coalesced ---------
__global__ __launch_bounds__(256) void gemm_qkv_all(const unsigned short* __restrict__ WbA,
    const unsigned short* __restrict__ xdwTA, const float* __restrict__ biasA,
    const unsigned short* __restrict__ posTA, unsigned short* __restrict__ Qf,
    unsigned short* __restrict__ Kf, unsigned short* __restrict__ Vf) {
  int by = blockIdx.y;
  int Ns, off;
  const unsigned short *Wb, *xdwT, *posT;
  const float* bias;
  if (by < 64) {
    Ns = 4096; off = 0;
    Wb = WbA; bias = biasA;
  } else if (by < 80) {
    Ns = 1024; off = 1048576; by -= 64;
    Wb = WbA + 196608; bias = biasA + 768;
  } else {
    Ns = 256; off = 1310720; by -= 80;
    Wb = WbA + 393216; bias = biasA + 1536;
  }
  xdwT = xdwTA + off; posT = posTA + off;
  const int t = threadIdx.x;
  const int wave = t >> 6, lane = t & 63;
  const int ln = lane & 15, quad = lane >> 4;
  const int o0 = blockIdx.x * 64 + (wave & 1) * 32;
  const int n0 = by * 64 + (wave >> 1) * 32;
  const int at0 = (o0 >> 4) * 8, at1 = at0 + 8;
  const int bt0 = (n0 >> 4) * 8, bt1 = bt0 + 8;
  const bool vblk = blockIdx.x >= 8;
  f32x4 acc[2][2] = {};
  if (!vblk) {
    #pragma unroll
    for (int ks = 0; ks < 8; ++ks) {
      bf16x8 af0 = *(const bf16x8*)(Wb + (size_t)(at0 + ks) * 512 + lane * 8);
      bf16x8 af1 = *(const bf16x8*)(Wb + (size_t)(at1 + ks) * 512 + lane * 8);
      bf16x8 bv0 = *(const bf16x8*)(xdwT + (size_t)(bt0 + ks) * 512 + lane * 8);
      bf16x8 bv1 = *(const bf16x8*)(xdwT + (size_t)(bt1 + ks) * 512 + lane * 8);
      acc[0][0] = __builtin_amdgcn_mfma_f32_16x16x32_bf16(af0, bv0, acc[0][0], 0, 0, 0);
      acc[0][1] = __builtin_amdgcn_mfma_f32_16x16x32_bf16(af0, bv1, acc[0][1], 0, 0, 0);
      acc[1][0] = __builtin_amdgcn_mfma_f32_16x16x32_bf16(af1, bv0, acc[1][0], 0, 0, 0);
      acc[1][1] = __builtin_amdgcn_mfma_f32_16x16x32_bf16(af1, bv1, acc[1][1], 0, 0, 0);
    }
  } else {
    #pragma unroll
    for (int ks = 0; ks < 8; ++ks) {
      bf16x8 af0 = *(const bf16x8*)(Wb + (size_t)(at0 + ks) * 512 + lane * 8);
      bf16x8 af1 = *(const bf16x8*)(Wb + (size_t)(at1 + ks) * 512 + lane * 8);
      bf16x8 bv0 = *(const bf16x8*)(xdwT + (size_t)(bt0 + ks) * 512 + lane * 8);
      bf16x8 bv1 = *(const bf16x8*)(xdwT + (size_t)(bt1 + ks) * 512 + lane * 8);
      // swapped: C^T -> row = n, col = o
      acc[0][0] = __builtin_amdgcn_mfma_f32_16x16x32_bf16(bv0, af0, acc[0][0], 0, 0, 0);
      acc[0][1] = __builtin_amdgcn_mfma_f32_16x16x32_bf16(bv0, af1, acc[0][1], 0, 0, 0);
      acc[1][0] = __builtin_amdgcn_mfma_f32_16x16x32_bf16(bv1, af0, acc[1][0], 0, 0, 0);
      acc[1][1] = __builtin_amdgcn_mfma_f32_16x16x32_bf16(bv1, af1, acc[1][1], 0, 0, 0);
    }
  }
  if (!vblk) {                                      // q or k: rows=o, cols=n
    const int cat = blockIdx.x >> 2;                // 0=q, 1=k
    #pragma unroll
    for (int mt = 0; mt < 2; ++mt) {
      int ot = o0 + mt * 16 + quad * 4;
      float bs0 = bias[ot], bs1 = bias[ot + 1], bs2 = bias[ot + 2], bs3 = bias[ot + 3];
      int cb = ot & 255;
      #pragma unroll
      for (int nt = 0; nt < 2; ++nt) {
        int nn = n0 + nt * 16 + ln;
        f32x4 v = acc[mt][nt];
        const unsigned short* pp = posT + (size_t)cb * Ns + nn;
        v.x += bs0 + bf2f(pp[0]);
        v.y += bs1 + bf2f(pp[Ns]);
        v.z += bs2 + bf2f(pp[2 * Ns]);
        v.w += bs3 + bf2f(pp[3 * Ns]);
        if (cat == 0) { v.x *= QSCALE; v.y *= QSCALE; v.z *= QSCALE; v.w *= QSCALE; }
        ushort4 st;
        st.x = f2bf(v.x); st.y = f2bf(v.y); st.z = f2bf(v.z); st.w = f2bf(v.w);
        int hh = cb >> 5, d = cb & 31;
        unsigned short* dst = (cat == 0 ? Qf : Kf) + off;
        size_t a = ((size_t)(hh * (Ns >> 4) + (nn >> 4)) * 64 + (d >> 3) * 16 + (nn & 15)) * 8
                   + (d & 7);
        *(ushort4*)(dst + a) = st;
      }
    }
  } else {                                          // v: rows=n, cols=o
    #pragma unroll
    for (int a = 0; a < 2; ++a) {
      int nbase = n0 + a * 16 + quad * 4;
      #pragma unroll
      for (int bb = 0; bb < 2; ++bb) {
        int o = o0 + bb * 16 + ln;
        int c = o - 512;
        int hh = c >> 5, d = c & 31;
        int dt = d >> 4, dl = d & 15;
        float bs = bias[o];
        f32x4 v = acc[a][bb];
        ushort4 st;
        st.x = f2bf(v.x + bs); st.y = f2bf(v.y + bs);
        st.z = f2bf(v.z + bs); st.w = f2bf(v.w + bs);
        size_t adr = ((((size_t)hh * (Ns >> 5) + (nbase >> 5)) * 2 + dt) * 64
                      + ((nbase & 31) >> 3) * 16 + dl) * 8 + (nbase & 7);
        *(ushort4*)(Vf + off + adr) = st;
      }
    }
  }
}

// ---------------- attention: fragment-layout direct loads + MFMA row-sums -------
// z 0..7: s1 splits; z 8..15: s2 splits (x<8); z 16..19: s4 splits (x<2).
__global__ __launch_bounds__(256) void attn_all_kernel(
    const unsigned short* __restrict__ Qf, const unsigned short* __restrict__ Kf,
    const unsigned short* __restrict__ Vf,
    unsigned short* __restrict__ accp1, unsigned short* __restrict__ p2,
    unsigned short* __restrict__ p4, float* __restrict__ ls1,
    float* __restrict__ ls2, float* __restrict__ ls4) {
  __shared__ unsigned short pt_lds[4 * 32 * 72];    // wave-private P^T [n][m], pad 72
  const int z = blockIdx.z;
  unsigned short* accp;
  float* lsump;
  int Ns, lgMs, sp, off;
  if (z < 8) {
    accp = accp1; lsump = ls1; Ns = 4096; lgMs = 9; sp = z; off = 0;
  } else if (z < 16) {
    if (blockIdx.x >= 8) return;
    accp = p2; lsump = ls2; Ns = 1024; lgMs = 7; sp = z - 8; off = 1048576;
  } else {
    if (blockIdx.x >= 2) return;
    accp = p4; lsump = ls4; Ns = 256; lgMs = 6; sp = z - 16; off = 1310720;
  }
  const int t = threadIdx.x;
  const int wave = t >> 6, lane = t & 63;
  const int ln = lane & 15, quad = lane >> 4;
  const int h = blockIdx.y;
  const int n0 = blockIdx.x * 128 + wave * 32;
  const unsigned short* qp = Qf + off
      + ((size_t)(h * (Ns >> 4) + (n0 >> 4)) * 64 + lane) * 8;
  bf16x8 qf0 = *(const bf16x8*)(qp);
  bf16x8 qf1 = *(const bf16x8*)(qp + 512);
  unsigned short* ptw = pt_lds + wave * (32 * 72);
  f32x4 acc[2][2] = {};
  f32x4 acc_l0 = {0.f, 0.f, 0.f, 0.f}, acc_l1 = {0.f, 0.f, 0.f, 0.f};
  const f32x4 zero = {0.f, 0.f, 0.f, 0.f};
  const short kOne = (short)0x3F80;                 // bf16 1.0
  const bf16x8 onesf = {kOne, kOne, kOne, kOne, kOne, kOne, kOne, kOne};
  const int m0s = sp << lgMs;
  const int nch = 1 << (lgMs - 6);
  const unsigned short* kp = Kf + off
      + ((size_t)(h * (Ns >> 4) + (m0s >> 4)) * 64 + lane) * 8;
  const unsigned short* vp = Vf + off
      + (((size_t)h * (Ns >> 5) + (m0s >> 5)) * 128 + lane) * 8;
  for (int ch = 0; ch < nch; ++ch) {
    const unsigned short* kc = kp + ch * 2048;
    const unsigned short* vc = vp + ch * 2048;
    bf16x8 kf0 = *(const bf16x8*)(kc);
    bf16x8 kf1 = *(const bf16x8*)(kc + 512);
    bf16x8 kf2 = *(const bf16x8*)(kc + 1024);
    bf16x8 kf3 = *(const bf16x8*)(kc + 1536);
    bf16x8 vf00 = *(const bf16x8*)(vc);          // ks0, dt0
    bf16x8 vf10 = *(const bf16x8*)(vc + 512);    // ks0, dt1
    bf16x8 vf01 = *(const bf16x8*)(vc + 1024);   // ks1, dt0
    bf16x8 vf11 = *(const bf16x8*)(vc + 1536);   // ks1, dt1
    f32x4 s[4][2];
    s[0][0] = __builtin_amdgcn_mfma_f32_16x16x32_bf16(kf0, qf0, zero, 0, 0, 0);
    s[0][1] = __builtin_amdgcn_mfma_f32_16x16x32_bf16(kf0, qf1, zero, 0, 0, 0);
    s[1][0] = __builtin_amdgcn_mfma_f32_16x16x32_bf16(kf1, qf0, zero, 0, 0, 0);
    s[1][1] = __builtin_amdgcn_mfma_f32_16x16x32_bf16(kf1, qf1, zero, 0, 0, 0);
    s[2][0] = __builtin_amdgcn_mfma_f32_16x16x32_bf16(kf2, qf0, zero, 0, 0, 0);
    s[2][1] = __builtin_amdgcn_mfma_f32_16x16x32_bf16(kf2, qf1, zero, 0, 0, 0);
    s[3][0] = __builtin_amdgcn_mfma_f32_16x16x32_bf16(kf3, qf0, zero, 0, 0, 0);
    s[3][1] = __builtin_amdgcn_mfma_f32_16x16x32_bf16(kf3, qf1, zero, 0, 0, 0);
    #pragma unroll
    for (int mt = 0; mt < 4; ++mt) {
      #pragma unroll
      for (int nt = 0; nt < 2; ++nt) {
        float e0 = EXP2(s[mt][nt].x);
        float e1 = EXP2(s[mt][nt].y);
        float e2 = EXP2(s[mt][nt].z);
        float e3 = EXP2(s[mt][nt].w);
        uint2 pk;                                   // bf16-truncate pack, 1 op/pair
        pk.x = __builtin_amdgcn_perm(__float_as_uint(e1), __float_as_uint(e0), 0x07060302);
        pk.y = __builtin_amdgcn_perm(__float_as_uint(e3), __float_as_uint(e2), 0x07060302);
        *(uint2*)&ptw[(nt * 16 + ln) * 72 + mt * 16 + quad * 4] = pk;
      }
    }
    #pragma unroll
    for (int ks = 0; ks < 2; ++ks) {
      bf16x8 pf0 = *(const bf16x8*)&ptw[ln * 72 + ks * 32 + quad * 8];
      bf16x8 pf1 = *(const bf16x8*)&ptw[(16 + ln) * 72 + ks * 32 + quad * 8];
      bf16x8 va = ks ? vf01 : vf00;
      bf16x8 vbf = ks ? vf11 : vf10;
      acc[0][0] = __builtin_amdgcn_mfma_f32_16x16x32_bf16(va, pf0, acc[0][0], 0, 0, 0);
      acc[0][1] = __builtin_amdgcn_mfma_f32_16x16x32_bf16(va, pf1, acc[0][1], 0, 0, 0);
      acc[1][0] = __builtin_amdgcn_mfma_f32_16x16x32_bf16(vbf, pf0, acc[1][0], 0, 0, 0);
      acc[1][1] = __builtin_amdgcn_mfma_f32_16x16x32_bf16(vbf, pf1, acc[1][1], 0, 0, 0);
      acc_l0 = __builtin_amdgcn_mfma_f32_16x16x32_bf16(onesf, pf0, acc_l0, 0, 0, 0);
      acc_l1 = __builtin_amdgcn_mfma_f32_16x16x32_bf16(onesf, pf1, acc_l1, 0, 0, 0);
    }
  }
  unsigned short* ap = accp + ((size_t)sp * 256 + h * 32) * Ns;
  #pragma unroll
  for (int dt = 0; dt < 2; ++dt) {
    #pragma unroll
    for (int r = 0; r < 4; ++r) {
      int cl = dt * 16 + quad * 4 + r;
      ap[(size_t)cl * Ns + n0 + ln]      = f2bf(((const float*)&acc[dt][0])[r]);
      ap[(size_t)cl * Ns + n0 + 16 + ln] = f2bf(((const float*)&acc[dt][1])[r]);
    }
  }
  if (lane < 16) {
    float* lp = lsump + ((size_t)sp * 8 + h) * Ns + n0;
    lp[lane]      = acc_l0.x;                       // all rows of ones-MFMA equal lsum_n
    lp[16 + lane] = acc_l1.x;
  }
}

// ---------------- combine s2 (8 splits) + s4 (4 splits) in one launch -----------
__global__ __launch_bounds__(256) void combine24_kernel(const unsigned short* __restrict__ p2,
    const float* __restrict__ ls2, const unsigned short* __restrict__ p4,
    const float* __restrict__ ls4, float* __restrict__ out2, float* __restrict__ out4) {
  int id = blockIdx.x * 256 + threadIdx.x;
  if (id < 262144) {                                // s2: 256 x 1024
    int n = id & 1023, h = id >> 15;
    float v = 0.f, d = 0.f;
    #pragma unroll
    for (int sp = 0; sp < 8; ++sp) {
      v += bf2f(p2[sp * 262144 + id]);
      d += ls2[sp * 8192 + h * 1024 + n];
    }
    out2[id] = v / d;
  } else {                                          // s4: 256 x 256
    int idl = id - 262144;
    int n = idl & 255, h = idl >> 13;
    float v = 0.f, d = 0.f;
    #pragma unroll
    for (int sp = 0; sp < 4; ++sp) {
      v += bf2f(p4[sp * 65536 + idl]);
      d += ls4[sp * 2048 + h * 256 + n];
    }
    out4[idl] = v / d;
  }
}

// ---------------- build catT in FRAG layout (R=4096 rows n, K=768 cols c) -------
__global__ __launch_bounds__(256) void build_catT_kernel(const unsigned short* __restrict__ accp,
    const float* __restrict__ lsum1, const float* __restrict__ out2,
    const float* __restrict__ out4, unsigned short* __restrict__ catT) {
  __shared__ unsigned short lds[64][72];
  const int t = threadIdx.x;
  const int n0 = blockIdx.x * 64;
  const int by = blockIdx.y;
  const int c0 = by * 64;
  if (by < 4) {
    #pragma unroll
    for (int p = 0; p < 4; ++p) {
      int ct = p * 16 + (t >> 4);
      int c = c0 + ct;
      int h = c >> 5;
      int nn = (t & 15) * 4;
      float vs[4] = {0.f, 0.f, 0.f, 0.f};
      float ds[4] = {0.f, 0.f, 0.f, 0.f};
      #pragma unroll
      for (int sp = 0; sp < 8; ++sp) {
        ushort4 a = *(const ushort4*)(accp + (size_t)sp * 1048576 + (size_t)c * 4096 + n0 + nn);
        vs[0] += bf2f(a.x); vs[1] += bf2f(a.y); vs[2] += bf2f(a.z); vs[3] += bf2f(a.w);
        float4 dd = *(const float4*)(lsum1 + (size_t)sp * 32768 + (size_t)h * 4096 + n0 + nn);
        ds[0] += dd.x; ds[1] += dd.y; ds[2] += dd.z; ds[3] += dd.w;
      }
      lds[nn + 0][ct] = f2bf(vs[0] / ds[0]);
      lds[nn + 1][ct] = f2bf(vs[1] / ds[1]);
      lds[nn + 2][ct] = f2bf(vs[2] / ds[2]);
      lds[nn + 3][ct] = f2bf(vs[3] / ds[3]);
    }
  } else {
    const bool s2 = by < 8;
    const float* src = s2 ? out2 : out4;
    const int Hs = s2 ? 32 : 16;
    const int coff = s2 ? 256 : 512;
    const float sc = (float)Hs / 64.0f;
    #pragma unroll
    for (int p = 0; p < 4; ++p) {
      int ct = p * 16 + (t >> 4);
      const float* s = src + (size_t)(c0 - coff + ct) * Hs * Hs;
      int nn = (t & 15) * 4;
      #pragma unroll
      for (int i = 0; i < 4; ++i) {
        int n = n0 + nn + i;
        int y = n >> 6, x = n & 63;
        float fy = ((float)y + 0.5f) * sc - 0.5f;
        float fx = ((float)x + 0.5f) * sc - 0.5f;
        float fy0 = floorf(fy), fx0 = floorf(fx);
        int y0 = (int)fy0, x0 = (int)fx0;
        float ty = fy - fy0, tx = fx - fx0;
        int y0c = min(max(y0, 0), Hs - 1), y1c = min(max(y0 + 1, 0), Hs - 1);
        int x0c = min(max(x0, 0), Hs - 1), x1c = min(max(x0 + 1, 0), Hs - 1);
        float v00 = s[y0c * Hs + x0c], v01 = s[y0c * Hs + x1c];
        float v10 = s[y1c * Hs + x0c], v11 = s[y1c * Hs + x1c];
        float v0 = v00 + (v01 - v00) * tx;
        float v1 = v10 + (v11 - v10) * tx;
        lds[nn + i][ct] = f2bf(v0 + (v1 - v0) * ty);
      }
    }
  }
  __syncthreads();
  // frag write: 8 blocks (4 n-tiles x 2 c-chunks) x 512 shorts, 32 threads each
  int blk = t >> 5, l = t & 31;
  int ntile = blk >> 1, cchunk = blk & 1;
  int koct = l >> 3, r1 = (l & 7) * 2;
  size_t bid = (size_t)((n0 >> 4) + ntile) * 24 + (c0 >> 5) + cchunk;
  unsigned short* dst = catT + bid * 512 + (size_t)l * 16;
  *(bf16x8*)(dst)     = *(const bf16x8*)&lds[ntile * 16 + r1][cchunk * 32 + koct * 8];
  *(bf16x8*)(dst + 8) = *(const bf16x8*)&lds[ntile * 16 + r1 + 1][cchunk * 32 + koct * 8];
}

// ---------------- fusion GEMM: frag loads, swapped operands, float4 stores ------
__global__ __launch_bounds__(256) void gemm_fus_mfma(const unsigned short* __restrict__ Wf,
    const unsigned short* __restrict__ catT, float* __restrict__ part) {
  const int t = threadIdx.x;
  const int wave = t >> 6, lane = t & 63;
  const int ln = lane & 15, quad = lane >> 4;
  const int o0 = blockIdx.x * 64 + (wave & 1) * 32;
  const int n0 = blockIdx.y * 64 + (wave >> 1) * 32;
  const int sp = blockIdx.z;
  const int at0 = (o0 >> 4) * 24 + sp * 8, at1 = at0 + 24;
  const int bt0 = (n0 >> 4) * 24 + sp * 8, bt1 = bt0 + 24;
  f32x4 acc[2][2] = {};                             // [n-tile][o-tile] (C^T)
  #pragma unroll
  for (int ks = 0; ks < 8; ++ks) {
    bf16x8 af0 = *(const bf16x8*)(Wf + (size_t)(at0 + ks) * 512 + lane * 8);
    bf16x8 af1 = *(const bf16x8*)(Wf + (size_t)(at1 + ks) * 512 + lane * 8);
    bf16x8 bv0 = *(const bf16x8*)(catT + (size_t)(bt0 + ks) * 512 + lane * 8);
    bf16x8 bv1 = *(const bf16x8*)(catT + (size_t)(bt1 + ks) * 512 + lane * 8);
    acc[0][0] = __builtin_amdgcn_mfma_f32_16x16x32_bf16(bv0, af0, acc[0][0], 0, 0, 0);
    acc[0][1] = __builtin_amdgcn_mfma_f32_16x16x32_bf16(bv0, af1, acc[0][1], 0, 0, 0);
    acc[1][0] = __builtin_amdgcn_mfma_f32_16x16x32_bf16(bv1, af0, acc[1][0], 0, 0, 0);
    acc[1][1] = __builtin_amdgcn_mfma_f32_16x16x32_bf16(bv1, af1, acc[1][1], 0, 0, 0);
  }
  float* pp = part + (size_t)sp * 1048576;
  #pragma unroll
  for (int a = 0; a < 2; ++a) {
    int nbase = n0 + a * 16 + quad * 4;
    #pragma unroll
    for (int bb = 0; bb < 2; ++bb) {
      int o = o0 + bb * 16 + ln;
      float4 st;
      st.x = acc[a][bb].x; st.y = acc[a][bb].y; st.z = acc[a][bb].z; st.w = acc[a][bb].w;
      *(float4*)(pp + (size_t)o * 4096 + nbase) = st;
    }
  }
}

// ---------------- fusion combine: out = p0+p1+p2 + bias -------------------------
__global__ __launch_bounds__(256) void fus_combine_kernel(const float* __restrict__ part,
    const float* __restrict__ bias, float* __restrict__ out) {
  int id = blockIdx.x * 256 + threadIdx.x;          // float4 index
  int o = id >> 10;
  float4 v0 = *(const float4*)(part + id * 4);
  float4 v1 = *(const float4*)(part + 1048576 + id * 4);
  float4 v2 = *(const float4*)(part + 2097152 + id * 4);
  float bs = bias[o];
  float4 r;
  r.x = v0.x + v1.x + v2.x + bs;
  r.y = v0.y + v1.y + v2.y + bs;
  r.z = v0.z + v1.z + v2.z + bs;
  r.w = v0.w + v1.w + v2.w + bs;
  *(float4*)(out + id * 4) = r;
}

extern "C" void kernel_launch(void* const* d_in, const int* in_sizes, int n_in,
                              void* d_out, int out_size, void* d_ws, size_t ws_size,
                              hipStream_t stream) {
  const float* x     = (const float*)d_in[0];
  const float* dw_w  = (const float*)d_in[1];
  const float* dw_b  = (const float*)d_in[2];
  const float* pw_w  = (const float*)d_in[3];
  const float* pw_b  = (const float*)d_in[4];
  const float* pos_w = (const float*)d_in[5];
  const float* pos_b = (const float*)d_in[6];
  const float* fus_w = (const float*)d_in[7];
  const float* fus_b = (const float*)d_in[8];
  float* out = (float*)d_out;
  float* ws = (float*)d_ws;

  // ws layout (floats), total 12,058,624 fl = 46.0 MB (aliasing noted inline)
  float* scratch = ws;                       // 1,376,256  [attn s2/s4 bf16 partials]
  float* posF   = ws + 1376256;              // 1,376,256  [lsum1/2/4 + out2/out4]
  float* accpF  = ws + 2752512;              // 4,194,304  [xs2/xs4 early; s1 bf16 partials; fusion part]
  unsigned short* xdwT = (unsigned short*)(ws + 6946816);   // 1,376,256 us (frag)
  unsigned short* posTc = (unsigned short*)(ws + 7634944);  // 1,376,256 us ([c][Ns])
  unsigned short* Qf   = (unsigned short*)(ws + 8323072);   // 1,376,256 us
  unsigned short* Kf   = Qf + 1376256;                      // 1,376,256 us
  unsigned short* Vf   = (unsigned short*)(ws + 9699328);   // 1,376,256 us
  unsigned short* catT = (unsigned short*)(ws + 10387456);  // 3,145,728 us [Wb early]
  unsigned short* Wf   = (unsigned short*)(ws + 11960320);  //   196,608 us

  float* xs2 = accpF;                        // dead before attn-s1 writes accp
  float* xs4 = accpF + 262144;
  unsigned short* Wb = catT;                 // dead before build_catT writes catT
  unsigned short* accp = (unsigned short*)accpF;            // 8,388,608 us (8 splits)
  float* lsump1 = posF;                      // 262,144 (8sp x 8h x 4096)
  float* lsump2 = posF + 262144;             // 65,536
  float* lsump4 = posF + 327680;             // 8,192
  float* out2   = posF + 335872;             // 262,144
  float* out4   = posF + 598016;             // 65,536
  unsigned short* p2 = (unsigned short*)scratch;            // 2,097,152 us (8 splits)
  unsigned short* p4 = (unsigned short*)scratch + 2097152;  //   262,144 us (4 splits)
  float* part = accpF;                       // fusion partials (accp dead then)

  prep_kernel<<<1472, 256, 0, stream>>>(x, pw_w, fus_w, xs2, xs4, Wb, Wf);
  dwt_kernel<<<1344, 256, 0, stream>>>(x, xs2, xs4, dw_w, dw_b, pos_w, pos_b, xdwT, posTc);
  gemm_qkv_all<<<dim3(12, 84), 256, 0, stream>>>(Wb, xdwT, pw_b, posTc, Qf, Kf, Vf);

  attn_all_kernel<<<dim3(32, 8, 20), 256, 0, stream>>>(Qf, Kf, Vf, accp, p2, p4,
                                                       lsump1, lsump2, lsump4);
  combine24_kernel<<<1280, 256, 0, stream>>>(p2, lsump2, p4, lsump4, out2, out4);

  build_catT_kernel<<<dim3(64, 12), 256, 0, stream>>>(accp, lsump1, out2, out4, catT);
  gemm_fus_mfma<<<dim3(4, 64, 3), 256, 0, stream>>>(Wf, catT, part);
  fus_combine_kernel<<<1024, 256, 0, stream>>>(part, fus_b, out);
}

// Round 14
// 146.818 us; speedup vs baseline: 1.2472x; 1.0093x over previous
//
#include <hip/hip_runtime.h>
#include <math.h>

#define DIM 256
#define HEADS 8
#define HD 32
// log2(e)/sqrt(32): folded into stored Q so attention uses native exp2
#define QSCALE 0.25504526770295183f

typedef __attribute__((ext_vector_type(8))) short bf16x8;
typedef __attribute__((ext_vector_type(4))) float f32x4;

#if __has_builtin(__builtin_amdgcn_exp2f)
#define EXP2(x) __builtin_amdgcn_exp2f(x)
#else
#define EXP2(x) __expf((x) * 0.6931471805599453f)
#endif

__device__ __forceinline__ unsigned short f2bf(float f) {
  unsigned int u = __float_as_uint(f);
  unsigned int r = u + 0x7fff + ((u >> 16) & 1);   // round-to-nearest-even
  return (unsigned short)(r >> 16);
}
__device__ __forceinline__ float bf2f(unsigned short u) {
  return __uint_as_float(((unsigned int)u) << 16);
}

// MFMA frag layout for a bf16 matrix [R][K] (R%16==0, K%32==0):
//   block id = (r>>4)*(K/32) + (k>>5), 512 shorts per block
//   offset   = ((k&31)>>3)*128 + (r&15)*8 + (k&7)
// GEMM load: base + bid*512 + lane*8  (contiguous 1KB per wave)

// ---------------- prep: avgpools + weight cvts into FRAG layout -----------------
__global__ __launch_bounds__(256) void prep_kernel(const float* __restrict__ x,
    const float* __restrict__ pw_w, const float* __restrict__ fus_w,
    float* __restrict__ xs2, float* __restrict__ xs4,
    unsigned short* __restrict__ Wb, unsigned short* __restrict__ Wf) {
  const int gx = blockIdx.x, t = threadIdx.x;
  if (gx < 1024) {                                  // avgpool s=2 -> 256x32x32
    int id = gx * 256 + t;
    int c = id >> 10, n = id & 1023;
    int y = (n >> 5) << 1, x0 = (n & 31) << 1;
    const float* b = x + c * 4096 + y * 64 + x0;
    xs2[id] = (b[0] + b[1] + b[64] + b[65]) * 0.25f;
  } else if (gx < 1280) {                           // avgpool s=4 -> 256x16x16
    int id = (gx - 1024) * 256 + t;
    int c = id >> 8, n = id & 255;
    int y = (n >> 4) << 2, x0 = (n & 15) << 2;
    const float* b = x + c * 4096 + y * 64 + x0;
    float s = 0.f;
    #pragma unroll
    for (int dy = 0; dy < 4; ++dy)
      #pragma unroll
      for (int dx = 0; dx < 4; ++dx) s += b[dy * 64 + dx];
    xs4[id] = s * 0.0625f;
  } else if (gx < 1424) {                           // pw_w -> Wb frag (3x768x256)
    int lid = (gx - 1280) * 256 + t;
    int fb = lid >> 5, l = lid & 31;                // fb < 1152
    int scale = fb / 384, bs = fb - scale * 384;
    int rtile = bs >> 3, kchunk = bs & 7;
    int r = scale * 768 + rtile * 16 + (l & 7) * 2;
    int k = kchunk * 32 + (l >> 3) * 8;
    const float* s0 = pw_w + (size_t)r * 256 + k;
    float4 u0 = *(const float4*)(s0);
    float4 u1 = *(const float4*)(s0 + 4);
    float4 u2 = *(const float4*)(s0 + 256);
    float4 u3 = *(const float4*)(s0 + 260);
    unsigned short* d = Wb + (size_t)fb * 512 + l * 16;
    ushort4 a0 = {f2bf(u0.x), f2bf(u0.y), f2bf(u0.z), f2bf(u0.w)};
    ushort4 a1 = {f2bf(u1.x), f2bf(u1.y), f2bf(u1.z), f2bf(u1.w)};
    ushort4 a2 = {f2bf(u2.x), f2bf(u2.y), f2bf(u2.z), f2bf(u2.w)};
    ushort4 a3 = {f2bf(u3.x), f2bf(u3.y), f2bf(u3.z), f2bf(u3.w)};
    *(ushort4*)(d)      = a0;
    *(ushort4*)(d + 4)  = a1;
    *(ushort4*)(d + 8)  = a2;
    *(ushort4*)(d + 12) = a3;
  } else {                                          // fus_w -> Wf frag (256x768)
    int lid = (gx - 1424) * 256 + t;
    int fb = lid >> 5, l = lid & 31;                // fb < 384
    int rtile = fb / 24, kchunk = fb - rtile * 24;
    int r = rtile * 16 + (l & 7) * 2;
    int k = kchunk * 32 + (l >> 3) * 8;
    const float* s0 = fus_w + (size_t)r * 768 + k;
    float4 u0 = *(const float4*)(s0);
    float4 u1 = *(const float4*)(s0 + 4);
    float4 u2 = *(const float4*)(s0 + 768);
    float4 u3 = *(const float4*)(s0 + 772);
    unsigned short* d = Wf + (size_t)fb * 512 + l * 16;
    ushort4 a0 = {f2bf(u0.x), f2bf(u0.y), f2bf(u0.z), f2bf(u0.w)};
    ushort4 a1 = {f2bf(u1.x), f2bf(u1.y), f2bf(u1.z), f2bf(u1.w)};
    ushort4 a2 = {f2bf(u2.x), f2bf(u2.y), f2bf(u2.z), f2bf(u2.w)};
    ushort4 a3 = {f2bf(u3.x), f2bf(u3.y), f2bf(u3.z), f2bf(u3.w)};
    *(ushort4*)(d)      = a0;
    *(ushort4*)(d + 4)  = a1;
    *(ushort4*)(d + 8)  = a2;
    *(ushort4*)(d + 12) = a3;
  }
}

// ---------------- fused dwconv(dw+pos): xdwT FRAG layout, posTc [c][Ns] ---------
// 32c x 32n per block, 1 c-position/thread. 1344 blocks.
__global__ __launch_bounds__(256) void dwt_kernel(const float* __restrict__ x,
    const float* __restrict__ xs2, const float* __restrict__ xs4,
    const float* __restrict__ dw_w, const float* __restrict__ dw_b,
    const float* __restrict__ pos_w, const float* __restrict__ pos_b,
    unsigned short* __restrict__ xdwT, unsigned short* __restrict__ posTc) {
  __shared__ __align__(16) unsigned short lds1[32][40];
  int b = blockIdx.x;
  const float* src;
  int lgHs, wo, soff;
  if (b < 1024)      { src = x;   lgHs = 6; wo = 0; soff = 0; }
  else if (b < 1280) { b -= 1024; src = xs2; lgHs = 5; wo = 1; soff = 1048576; }
  else               { b -= 1280; src = xs4; lgHs = 4; wo = 2; soff = 1310720; }
  const int c0 = (b & 7) * 32;
  const int n0 = (b >> 3) * 32;
  const int Hs = 1 << lgHs;
  const int Ns = Hs * Hs;
  const int t = threadIdx.x;
  const int cl = t >> 3;
  const int c = c0 + cl;
  const int nb = (t & 7) * 4;
  const float* w1 = dw_w + wo * 2304 + c * 9;
  const float* w2 = pos_w + wo * 2304 + c * 9;
  const float b1 = dw_b[wo * 256 + c], b2 = pos_b[wo * 256 + c];
  const int gn = n0 + nb;
  const int y = gn >> lgHs, xg = gn & (Hs - 1);
  const float* sc = src + c * Ns;
  float r[3][6];
  #pragma unroll
  for (int ky = 0; ky < 3; ++ky) {
    int yy = y + ky - 1;
    bool rok = (yy >= 0) && (yy < Hs);
    #pragma unroll
    for (int j = 0; j < 6; ++j) {
      int xx = xg - 1 + j;
      r[ky][j] = (rok && xx >= 0 && xx < Hs) ? sc[yy * Hs + xx] : 0.f;
    }
  }
  ushort4 pst;
  unsigned short* ps = (unsigned short*)&pst;
  #pragma unroll
  for (int i = 0; i < 4; ++i) {
    float s1 = b1, s2 = b2;
    #pragma unroll
    for (int ky = 0; ky < 3; ++ky)
      #pragma unroll
      for (int kx = 0; kx < 3; ++kx) {
        float v = r[ky][i + kx];
        s1 += v * w1[ky * 3 + kx];
        s2 += v * w2[ky * 3 + kx];
      }
    lds1[nb + i][cl] = f2bf(s1);
    ps[i] = f2bf(s2);
  }
  *(ushort4*)(posTc + soff + (size_t)c * Ns + gn) = pst;
  __syncthreads();
  if (t < 128) {                                    // 2 frag blocks x 512 shorts
    int blk = t >> 6, l = t & 63;
    size_t bid = (size_t)((n0 >> 4) + blk) * 8 + (c0 >> 5);
    *(bf16x8*)(xdwT + soff + bid * 512 + (size_t)l * 8) =
        *(const bf16x8*)&lds1[blk * 16 + (l & 15)][(l >> 4) * 8];
  }
}

// ---------------- QKV GEMM, frag loads -> frag outputs; posTc coalesced ---------
__global__ __launch_bounds__(256) void gemm_qkv_all(const unsigned short* __restrict__ WbA,
    const unsigned short* __restrict__ xdwTA, const float* __restrict__ biasA,
    const unsigned short* __restrict__ posTA, unsigned short* __restrict__ Qf,
    unsigned short* __restrict__ Kf, unsigned short* __restrict__ Vf) {
  int by = blockIdx.y;
  int Ns, off;
  const unsigned short *Wb, *xdwT, *posT;
  const float* bias;
  if (by < 64) {
    Ns = 4096; off = 0;
    Wb = WbA; bias = biasA;
  } else if (by < 80) {
    Ns = 1024; off = 1048576; by -= 64;
    Wb = WbA + 196608; bias = biasA + 768;
  } else {
    Ns = 256; off = 1310720; by -= 80;
    Wb = WbA + 393216; bias = biasA + 1536;
  }
  xdwT = xdwTA + off; posT = posTA + off;
  const int t = threadIdx.x;
  const int wave = t >> 6, lane = t & 63;
  const int ln = lane & 15, quad = lane >> 4;
  const int o0 = blockIdx.x * 64 + (wave & 1) * 32;
  const int n0 = by * 64 + (wave >> 1) * 32;
  const int at0 = (o0 >> 4) * 8, at1 = at0 + 8;
  const int bt0 = (n0 >> 4) * 8, bt1 = bt0 + 8;
  const bool vblk = blockIdx.x >= 8;
  f32x4 acc[2][2] = {};
  if (!vblk) {
    #pragma unroll
    for (int ks = 0; ks < 8; ++ks) {
      bf16x8 af0 = *(const bf16x8*)(Wb + (size_t)(at0 + ks) * 512 + lane * 8);
      bf16x8 af1 = *(const bf16x8*)(Wb + (size_t)(at1 + ks) * 512 + lane * 8);
      bf16x8 bv0 = *(const bf16x8*)(xdwT + (size_t)(bt0 + ks) * 512 + lane * 8);
      bf16x8 bv1 = *(const bf16x8*)(xdwT + (size_t)(bt1 + ks) * 512 + lane * 8);
      acc[0][0] = __builtin_amdgcn_mfma_f32_16x16x32_bf16(af0, bv0, acc[0][0], 0, 0, 0);
      acc[0][1] = __builtin_amdgcn_mfma_f32_16x16x32_bf16(af0, bv1, acc[0][1], 0, 0, 0);
      acc[1][0] = __builtin_amdgcn_mfma_f32_16x16x32_bf16(af1, bv0, acc[1][0], 0, 0, 0);
      acc[1][1] = __builtin_amdgcn_mfma_f32_16x16x32_bf16(af1, bv1, acc[1][1], 0, 0, 0);
    }
  } else {
    #pragma unroll
    for (int ks = 0; ks < 8; ++ks) {
      bf16x8 af0 = *(const bf16x8*)(Wb + (size_t)(at0 + ks) * 512 + lane * 8);
      bf16x8 af1 = *(const bf16x8*)(Wb + (size_t)(at1 + ks) * 512 + lane * 8);
      bf16x8 bv0 = *(const bf16x8*)(xdwT + (size_t)(bt0 + ks) * 512 + lane * 8);
      bf16x8 bv1 = *(const bf16x8*)(xdwT + (size_t)(bt1 + ks) * 512 + lane * 8);
      // swapped: C^T -> row = n, col = o
      acc[0][0] = __builtin_amdgcn_mfma_f32_16x16x32_bf16(bv0, af0, acc[0][0], 0, 0, 0);
      acc[0][1] = __builtin_amdgcn_mfma_f32_16x16x32_bf16(bv0, af1, acc[0][1], 0, 0, 0);
      acc[1][0] = __builtin_amdgcn_mfma_f32_16x16x32_bf16(bv1, af0, acc[1][0], 0, 0, 0);
      acc[1][1] = __builtin_amdgcn_mfma_f32_16x16x32_bf16(bv1, af1, acc[1][1], 0, 0, 0);
    }
  }
  if (!vblk) {                                      // q or k: rows=o, cols=n
    const int cat = blockIdx.x >> 2;                // 0=q, 1=k
    #pragma unroll
    for (int mt = 0; mt < 2; ++mt) {
      int ot = o0 + mt * 16 + quad * 4;
      float bs0 = bias[ot], bs1 = bias[ot + 1], bs2 = bias[ot + 2], bs3 = bias[ot + 3];
      int cb = ot & 255;
      #pragma unroll
      for (int nt = 0; nt < 2; ++nt) {
        int nn = n0 + nt * 16 + ln;
        f32x4 v = acc[mt][nt];
        const unsigned short* pp = posT + (size_t)cb * Ns + nn;
        v.x += bs0 + bf2f(pp[0]);
        v.y += bs1 + bf2f(pp[Ns]);
        v.z += bs2 + bf2f(pp[2 * Ns]);
        v.w += bs3 + bf2f(pp[3 * Ns]);
        if (cat == 0) { v.x *= QSCALE; v.y *= QSCALE; v.z *= QSCALE; v.w *= QSCALE; }
        ushort4 st;
        st.x = f2bf(v.x); st.y = f2bf(v.y); st.z = f2bf(v.z); st.w = f2bf(v.w);
        int hh = cb >> 5, d = cb & 31;
        unsigned short* dst = (cat == 0 ? Qf : Kf) + off;
        size_t a = ((size_t)(hh * (Ns >> 4) + (nn >> 4)) * 64 + (d >> 3) * 16 + (nn & 15)) * 8
                   + (d & 7);
        *(ushort4*)(dst + a) = st;
      }
    }
  } else {                                          // v: rows=n, cols=o
    #pragma unroll
    for (int a = 0; a < 2; ++a) {
      int nbase = n0 + a * 16 + quad * 4;
      #pragma unroll
      for (int bb = 0; bb < 2; ++bb) {
        int o = o0 + bb * 16 + ln;
        int c = o - 512;
        int hh = c >> 5, d = c & 31;
        int dt = d >> 4, dl = d & 15;
        float bs = bias[o];
        f32x4 v = acc[a][bb];
        ushort4 st;
        st.x = f2bf(v.x + bs); st.y = f2bf(v.y + bs);
        st.z = f2bf(v.z + bs); st.w = f2bf(v.w + bs);
        size_t adr = ((((size_t)hh * (Ns >> 5) + (nbase >> 5)) * 2 + dt) * 64
                      + ((nbase & 31) >> 3) * 16 + dl) * 8 + (nbase & 7);
        *(ushort4*)(Vf + off + adr) = st;
      }
    }
  }
}

// ---------------- attention: frag loads, 4 splits/scale, interleaved exp/PV -----
// z 0..3: s1 splits (lgMs=10); z 4..7: s2 (x<8, lgMs=8); z 8..11: s4 (x<2, lgMs=6).
// Chunk body interleaves: QK -> exp(mt0,mt1) -> PV ks0 (MFMA runs under exp(mt2,mt3))
// -> PV ks1. lsum via ones-MFMA.
__global__ __launch_bounds__(256) void attn_all_kernel(
    const unsigned short* __restrict__ Qf, const unsigned short* __restrict__ Kf,
    const unsigned short* __restrict__ Vf,
    unsigned short* __restrict__ accp1, unsigned short* __restrict__ p2,
    unsigned short* __restrict__ p4, float* __restrict__ ls1,
    float* __restrict__ ls2, float* __restrict__ ls4) {
  __shared__ unsigned short pt_lds[4 * 32 * 72];    // wave-private P^T [n][m], pad 72
  const int z = blockIdx.z;
  unsigned short* accp;
  float* lsump;
  int Ns, lgMs, sp, off;
  if (z < 4) {
    accp = accp1; lsump = ls1; Ns = 4096; lgMs = 10; sp = z; off = 0;
  } else if (z < 8) {
    if (blockIdx.x >= 8) return;
    accp = p2; lsump = ls2; Ns = 1024; lgMs = 8; sp = z - 4; off = 1048576;
  } else {
    if (blockIdx.x >= 2) return;
    accp = p4; lsump = ls4; Ns = 256; lgMs = 6; sp = z - 8; off = 1310720;
  }
  const int t = threadIdx.x;
  const int wave = t >> 6, lane = t & 63;
  const int ln = lane & 15, quad = lane >> 4;
  const int h = blockIdx.y;
  const int n0 = blockIdx.x * 128 + wave * 32;
  const unsigned short* qp = Qf + off
      + ((size_t)(h * (Ns >> 4) + (n0 >> 4)) * 64 + lane) * 8;
  bf16x8 qf0 = *(const bf16x8*)(qp);
  bf16x8 qf1 = *(const bf16x8*)(qp + 512);
  unsigned short* ptw = pt_lds + wave * (32 * 72);
  f32x4 acc[2][2] = {};
  f32x4 acc_l0 = {0.f, 0.f, 0.f, 0.f}, acc_l1 = {0.f, 0.f, 0.f, 0.f};
  const f32x4 zero = {0.f, 0.f, 0.f, 0.f};
  const short kOne = (short)0x3F80;                 // bf16 1.0
  const bf16x8 onesf = {kOne, kOne, kOne, kOne, kOne, kOne, kOne, kOne};
  const int m0s = sp << lgMs;
  const int nch = 1 << (lgMs - 6);
  const unsigned short* kp = Kf + off
      + ((size_t)(h * (Ns >> 4) + (m0s >> 4)) * 64 + lane) * 8;
  const unsigned short* vp = Vf + off
      + (((size_t)h * (Ns >> 5) + (m0s >> 5)) * 128 + lane) * 8;
  for (int ch = 0; ch < nch; ++ch) {
    const unsigned short* kc = kp + ch * 2048;
    const unsigned short* vc = vp + ch * 2048;
    bf16x8 kf0 = *(const bf16x8*)(kc);
    bf16x8 kf1 = *(const bf16x8*)(kc + 512);
    bf16x8 kf2 = *(const bf16x8*)(kc + 1024);
    bf16x8 kf3 = *(const bf16x8*)(kc + 1536);
    bf16x8 vf00 = *(const bf16x8*)(vc);          // ks0, dt0
    bf16x8 vf10 = *(const bf16x8*)(vc + 512);    // ks0, dt1
    bf16x8 vf01 = *(const bf16x8*)(vc + 1024);   // ks1, dt0
    bf16x8 vf11 = *(const bf16x8*)(vc + 1536);   // ks1, dt1
    f32x4 s[4][2];
    s[0][0] = __builtin_amdgcn_mfma_f32_16x16x32_bf16(kf0, qf0, zero, 0, 0, 0);
    s[0][1] = __builtin_amdgcn_mfma_f32_16x16x32_bf16(kf0, qf1, zero, 0, 0, 0);
    s[1][0] = __builtin_amdgcn_mfma_f32_16x16x32_bf16(kf1, qf0, zero, 0, 0, 0);
    s[1][1] = __builtin_amdgcn_mfma_f32_16x16x32_bf16(kf1, qf1, zero, 0, 0, 0);
    s[2][0] = __builtin_amdgcn_mfma_f32_16x16x32_bf16(kf2, qf0, zero, 0, 0, 0);
    s[2][1] = __builtin_amdgcn_mfma_f32_16x16x32_bf16(kf2, qf1, zero, 0, 0, 0);
    s[3][0] = __builtin_amdgcn_mfma_f32_16x16x32_bf16(kf3, qf0, zero, 0, 0, 0);
    s[3][1] = __builtin_amdgcn_mfma_f32_16x16x32_bf16(kf3, qf1, zero, 0, 0, 0);
    // exp+pack mt0,mt1 (cols 0..31 of ptw)
    #pragma unroll
    for (int mt = 0; mt < 2; ++mt) {
      #pragma unroll
      for (int nt = 0; nt < 2; ++nt) {
        float e0 = EXP2(s[mt][nt].x);
        float e1 = EXP2(s[mt][nt].y);
        float e2 = EXP2(s[mt][nt].z);
        float e3 = EXP2(s[mt][nt].w);
        uint2 pk;
        pk.x = __builtin_amdgcn_perm(__float_as_uint(e1), __float_as_uint(e0), 0x07060302);
        pk.y = __builtin_amdgcn_perm(__float_as_uint(e3), __float_as_uint(e2), 0x07060302);
        *(uint2*)&ptw[(nt * 16 + ln) * 72 + mt * 16 + quad * 4] = pk;
      }
    }
    // PV ks0 — its MFMAs execute while the mt2/mt3 exp VALU below issues
    {
      bf16x8 pf0 = *(const bf16x8*)&ptw[ln * 72 + quad * 8];
      bf16x8 pf1 = *(const bf16x8*)&ptw[(16 + ln) * 72 + quad * 8];
      acc[0][0] = __builtin_amdgcn_mfma_f32_16x16x32_bf16(vf00, pf0, acc[0][0], 0, 0, 0);
      acc[0][1] = __builtin_amdgcn_mfma_f32_16x16x32_bf16(vf00, pf1, acc[0][1], 0, 0, 0);
      acc[1][0] = __builtin_amdgcn_mfma_f32_16x16x32_bf16(vf10, pf0, acc[1][0], 0, 0, 0);
      acc[1][1] = __builtin_amdgcn_mfma_f32_16x16x32_bf16(vf10, pf1, acc[1][1], 0, 0, 0);
      acc_l0 = __builtin_amdgcn_mfma_f32_16x16x32_bf16(onesf, pf0, acc_l0, 0, 0, 0);
      acc_l1 = __builtin_amdgcn_mfma_f32_16x16x32_bf16(onesf, pf1, acc_l1, 0, 0, 0);
    }
    // exp+pack mt2,mt3 (cols 32..63)
    #pragma unroll
    for (int mt = 2; mt < 4; ++mt) {
      #pragma unroll
      for (int nt = 0; nt < 2; ++nt) {
        float e0 = EXP2(s[mt][nt].x);
        float e1 = EXP2(s[mt][nt].y);
        float e2 = EXP2(s[mt][nt].z);
        float e3 = EXP2(s[mt][nt].w);
        uint2 pk;
        pk.x = __builtin_amdgcn_perm(__float_as_uint(e1), __float_as_uint(e0), 0x07060302);
        pk.y = __builtin_amdgcn_perm(__float_as_uint(e3), __float_as_uint(e2), 0x07060302);
        *(uint2*)&ptw[(nt * 16 + ln) * 72 + mt * 16 + quad * 4] = pk;
      }
    }
    // PV ks1
    {
      bf16x8 pf0 = *(const bf16x8*)&ptw[ln * 72 + 32 + quad * 8];
      bf16x8 pf1 = *(const bf16x8*)&ptw[(16 + ln) * 72 + 32 + quad * 8];
      acc[0][0] = __builtin_amdgcn_mfma_f32_16x16x32_bf16(vf01, pf0, acc[0][0], 0, 0, 0);
      acc[0][1] = __builtin_amdgcn_mfma_f32_16x16x32_bf16(vf01, pf1, acc[0][1], 0, 0, 0);
      acc[1][0] = __builtin_amdgcn_mfma_f32_16x16x32_bf16(vf11, pf0, acc[1][0], 0, 0, 0);
      acc[1][1] = __builtin_amdgcn_mfma_f32_16x16x32_bf16(vf11, pf1, acc[1][1], 0, 0, 0);
      acc_l0 = __builtin_amdgcn_mfma_f32_16x16x32_bf16(onesf, pf0, acc_l0, 0, 0, 0);
      acc_l1 = __builtin_amdgcn_mfma_f32_16x16x32_bf16(onesf, pf1, acc_l1, 0, 0, 0);
    }
  }
  unsigned short* ap = accp + ((size_t)sp * 256 + h * 32) * Ns;
  #pragma unroll
  for (int dt = 0; dt < 2; ++dt) {
    #pragma unroll
    for (int r = 0; r < 4; ++r) {
      int cl = dt * 16 + quad * 4 + r;
      ap[(size_t)cl * Ns + n0 + ln]      = f2bf(((const float*)&acc[dt][0])[r]);
      ap[(size_t)cl * Ns + n0 + 16 + ln] = f2bf(((const float*)&acc[dt][1])[r]);
    }
  }
  if (lane < 16) {
    float* lp = lsump + ((size_t)sp * 8 + h) * Ns + n0;
    lp[lane]      = acc_l0.x;                       // all rows of ones-MFMA equal lsum_n
    lp[16 + lane] = acc_l1.x;
  }
}

// ---------------- combine s2 (4 splits) + s4 (4 splits) in one launch -----------
__global__ __launch_bounds__(256) void combine24_kernel(const unsigned short* __restrict__ p2,
    const float* __restrict__ ls2, const unsigned short* __restrict__ p4,
    const float* __restrict__ ls4, float* __restrict__ out2, float* __restrict__ out4) {
  int id = blockIdx.x * 256 + threadIdx.x;
  if (id < 262144) {                                // s2: 256 x 1024
    int n = id & 1023, h = id >> 15;
    float v = 0.f, d = 0.f;
    #pragma unroll
    for (int sp = 0; sp < 4; ++sp) {
      v += bf2f(p2[sp * 262144 + id]);
      d += ls2[sp * 8192 + h * 1024 + n];
    }
    out2[id] = v / d;
  } else {                                          // s4: 256 x 256
    int idl = id - 262144;
    int n = idl & 255, h = idl >> 13;
    float v = 0.f, d = 0.f;
    #pragma unroll
    for (int sp = 0; sp < 4; ++sp) {
      v += bf2f(p4[sp * 65536 + idl]);
      d += ls4[sp * 2048 + h * 256 + n];
    }
    out4[idl] = v / d;
  }
}

// ---------------- build catT in FRAG layout (R=4096 rows n, K=768 cols c) -------
__global__ __launch_bounds__(256) void build_catT_kernel(const unsigned short* __restrict__ accp,
    const float* __restrict__ lsum1, const float* __restrict__ out2,
    const float* __restrict__ out4, unsigned short* __restrict__ catT) {
  __shared__ unsigned short lds[64][72];
  const int t = threadIdx.x;
  const int n0 = blockIdx.x * 64;
  const int by = blockIdx.y;
  const int c0 = by * 64;
  if (by < 4) {
    #pragma unroll
    for (int p = 0; p < 4; ++p) {
      int ct = p * 16 + (t >> 4);
      int c = c0 + ct;
      int h = c >> 5;
      int nn = (t & 15) * 4;
      float vs[4] = {0.f, 0.f, 0.f, 0.f};
      float ds[4] = {0.f, 0.f, 0.f, 0.f};
      #pragma unroll
      for (int sp = 0; sp < 4; ++sp) {
        ushort4 a = *(const ushort4*)(accp + (size_t)sp * 1048576 + (size_t)c * 4096 + n0 + nn);
        vs[0] += bf2f(a.x); vs[1] += bf2f(a.y); vs[2] += bf2f(a.z); vs[3] += bf2f(a.w);
        float4 dd = *(const float4*)(lsum1 + (size_t)sp * 32768 + (size_t)h * 4096 + n0 + nn);
        ds[0] += dd.x; ds[1] += dd.y; ds[2] += dd.z; ds[3] += dd.w;
      }
      lds[nn + 0][ct] = f2bf(vs[0] / ds[0]);
      lds[nn + 1][ct] = f2bf(vs[1] / ds[1]);
      lds[nn + 2][ct] = f2bf(vs[2] / ds[2]);
      lds[nn + 3][ct] = f2bf(vs[3] / ds[3]);
    }
  } else {
    const bool s2 = by < 8;
    const float* src = s2 ? out2 : out4;
    const int Hs = s2 ? 32 : 16;
    const int coff = s2 ? 256 : 512;
    const float sc = (float)Hs / 64.0f;
    #pragma unroll
    for (int p = 0; p < 4; ++p) {
      int ct = p * 16 + (t >> 4);
      const float* s = src + (size_t)(c0 - coff + ct) * Hs * Hs;
      int nn = (t & 15) * 4;
      #pragma unroll
      for (int i = 0; i < 4; ++i) {
        int n = n0 + nn + i;
        int y = n >> 6, x = n & 63;
        float fy = ((float)y + 0.5f) * sc - 0.5f;
        float fx = ((float)x + 0.5f) * sc - 0.5f;
        float fy0 = floorf(fy), fx0 = floorf(fx);
        int y0 = (int)fy0, x0 = (int)fx0;
        float ty = fy - fy0, tx = fx - fx0;
        int y0c = min(max(y0, 0), Hs - 1), y1c = min(max(y0 + 1, 0), Hs - 1);
        int x0c = min(max(x0, 0), Hs - 1), x1c = min(max(x0 + 1, 0), Hs - 1);
        float v00 = s[y0c * Hs + x0c], v01 = s[y0c * Hs + x1c];
        float v10 = s[y1c * Hs + x0c], v11 = s[y1c * Hs + x1c];
        float v0 = v00 + (v01 - v00) * tx;
        float v1 = v10 + (v11 - v10) * tx;
        lds[nn + i][ct] = f2bf(v0 + (v1 - v0) * ty);
      }
    }
  }
  __syncthreads();
  // frag write: 8 blocks (4 n-tiles x 2 c-chunks) x 512 shorts, 32 threads each
  int blk = t >> 5, l = t & 31;
  int ntile = blk >> 1, cchunk = blk & 1;
  int koct = l >> 3, r1 = (l & 7) * 2;
  size_t bid = (size_t)((n0 >> 4) + ntile) * 24 + (c0 >> 5) + cchunk;
  unsigned short* dst = catT + bid * 512 + (size_t)l * 16;
  *(bf16x8*)(dst)     = *(const bf16x8*)&lds[ntile * 16 + r1][cchunk * 32 + koct * 8];
  *(bf16x8*)(dst + 8) = *(const bf16x8*)&lds[ntile * 16 + r1 + 1][cchunk * 32 + koct * 8];
}

// ---------------- fusion GEMM: frag loads, swapped operands, float4 stores ------
__global__ __launch_bounds__(256) void gemm_fus_mfma(const unsigned short* __restrict__ Wf,
    const unsigned short* __restrict__ catT, float* __restrict__ part) {
  const int t = threadIdx.x;
  const int wave = t >> 6, lane = t & 63;
  const int ln = lane & 15, quad = lane >> 4;
  const int o0 = blockIdx.x * 64 + (wave & 1) * 32;
  const int n0 = blockIdx.y * 64 + (wave >> 1) * 32;
  const int sp = blockIdx.z;
  const int at0 = (o0 >> 4) * 24 + sp * 8, at1 = at0 + 24;
  const int bt0 = (n0 >> 4) * 24 + sp * 8, bt1 = bt0 + 24;
  f32x4 acc[2][2] = {};                             // [n-tile][o-tile] (C^T)
  #pragma unroll
  for (int ks = 0; ks < 8; ++ks) {
    bf16x8 af0 = *(const bf16x8*)(Wf + (size_t)(at0 + ks) * 512 + lane * 8);
    bf16x8 af1 = *(const bf16x8*)(Wf + (size_t)(at1 + ks) * 512 + lane * 8);
    bf16x8 bv0 = *(const bf16x8*)(catT + (size_t)(bt0 + ks) * 512 + lane * 8);
    bf16x8 bv1 = *(const bf16x8*)(catT + (size_t)(bt1 + ks) * 512 + lane * 8);
    acc[0][0] = __builtin_amdgcn_mfma_f32_16x16x32_bf16(bv0, af0, acc[0][0], 0, 0, 0);
    acc[0][1] = __builtin_amdgcn_mfma_f32_16x16x32_bf16(bv0, af1, acc[0][1], 0, 0, 0);
    acc[1][0] = __builtin_amdgcn_mfma_f32_16x16x32_bf16(bv1, af0, acc[1][0], 0, 0, 0);
    acc[1][1] = __builtin_amdgcn_mfma_f32_16x16x32_bf16(bv1, af1, acc[1][1], 0, 0, 0);
  }
  float* pp = part + (size_t)sp * 1048576;
  #pragma unroll
  for (int a = 0; a < 2; ++a) {
    int nbase = n0 + a * 16 + quad * 4;
    #pragma unroll
    for (int bb = 0; bb < 2; ++bb) {
      int o = o0 + bb * 16 + ln;
      float4 st;
      st.x = acc[a][bb].x; st.y = acc[a][bb].y; st.z = acc[a][bb].z; st.w = acc[a][bb].w;
      *(float4*)(pp + (size_t)o * 4096 + nbase) = st;
    }
  }
}

// ---------------- fusion combine: out = p0+p1+p2 + bias -------------------------
__global__ __launch_bounds__(256) void fus_combine_kernel(const float* __restrict__ part,
    const float* __restrict__ bias, float* __restrict__ out) {
  int id = blockIdx.x * 256 + threadIdx.x;          // float4 index
  int o = id >> 10;
  float4 v0 = *(const float4*)(part + id * 4);
  float4 v1 = *(const float4*)(part + 1048576 + id * 4);
  float4 v2 = *(const float4*)(part + 2097152 + id * 4);
  float bs = bias[o];
  float4 r;
  r.x = v0.x + v1.x + v2.x + bs;
  r.y = v0.y + v1.y + v2.y + bs;
  r.z = v0.z + v1.z + v2.z + bs;
  r.w = v0.w + v1.w + v2.w + bs;
  *(float4*)(out + id * 4) = r;
}

extern "C" void kernel_launch(void* const* d_in, const int* in_sizes, int n_in,
                              void* d_out, int out_size, void* d_ws, size_t ws_size,
                              hipStream_t stream) {
  const float* x     = (const float*)d_in[0];
  const float* dw_w  = (const float*)d_in[1];
  const float* dw_b  = (const float*)d_in[2];
  const float* pw_w  = (const float*)d_in[3];
  const float* pw_b  = (const float*)d_in[4];
  const float* pos_w = (const float*)d_in[5];
  const float* pos_b = (const float*)d_in[6];
  const float* fus_w = (const float*)d_in[7];
  const float* fus_b = (const float*)d_in[8];
  float* out = (float*)d_out;
  float* ws = (float*)d_ws;

  // ws layout (floats), total 12,058,624 fl = 46.0 MB (aliasing noted inline)
  float* scratch = ws;                       // 1,376,256  [attn s2/s4 bf16 partials]
  float* posF   = ws + 1376256;              // 1,376,256  [lsum1/2/4 + out2/out4]
  float* accpF  = ws + 2752512;              // 4,194,304  [xs2/xs4 early; s1 bf16 partials; fusion part]
  unsigned short* xdwT = (unsigned short*)(ws + 6946816);   // 1,376,256 us (frag)
  unsigned short* posTc = (unsigned short*)(ws + 7634944);  // 1,376,256 us ([c][Ns])
  unsigned short* Qf   = (unsigned short*)(ws + 8323072);   // 1,376,256 us
  unsigned short* Kf   = Qf + 1376256;                      // 1,376,256 us
  unsigned short* Vf   = (unsigned short*)(ws + 9699328);   // 1,376,256 us
  unsigned short* catT = (unsigned short*)(ws + 10387456);  // 3,145,728 us [Wb early]
  unsigned short* Wf   = (unsigned short*)(ws + 11960320);  //   196,608 us

  float* xs2 = accpF;                        // dead before attn-s1 writes accp
  float* xs4 = accpF + 262144;
  unsigned short* Wb = catT;                 // dead before build_catT writes catT
  unsigned short* accp = (unsigned short*)accpF;            // 4,194,304 us (4 splits)
  float* lsump1 = posF;                      // 131,072 (4sp x 8h x 4096)
  float* lsump2 = posF + 262144;             // 32,768
  float* lsump4 = posF + 327680;             // 8,192
  float* out2   = posF + 335872;             // 262,144
  float* out4   = posF + 598016;             // 65,536
  unsigned short* p2 = (unsigned short*)scratch;            // 1,048,576 us (4 splits)
  unsigned short* p4 = (unsigned short*)scratch + 2097152;  //   262,144 us (4 splits)
  float* part = accpF;                       // fusion partials (accp dead then)

  prep_kernel<<<1472, 256, 0, stream>>>(x, pw_w, fus_w, xs2, xs4, Wb, Wf);
  dwt_kernel<<<1344, 256, 0, stream>>>(x, xs2, xs4, dw_w, dw_b, pos_w, pos_b, xdwT, posTc);
  gemm_qkv_all<<<dim3(12, 84), 256, 0, stream>>>(Wb, xdwT, pw_b, posTc, Qf, Kf, Vf);

  attn_all_kernel<<<dim3(32, 8, 12), 256, 0, stream>>>(Qf, Kf, Vf, accp, p2, p4,
                                                       lsump1, lsump2, lsump4);
  combine24_kernel<<<1280, 256, 0, stream>>>(p2, lsump2, p4, lsump4, out2, out4);

  build_catT_kernel<<<dim3(64, 12), 256, 0, stream>>>(accp, lsump1, out2, out4, catT);
  gemm_fus_mfma<<<dim3(4, 64, 3), 256, 0, stream>>>(Wf, catT, part);
  fus_combine_kernel<<<1024, 256, 0, stream>>>(part, fus_b, out);
}

// Round 16
// 146.722 us; speedup vs baseline: 1.2480x; 1.0007x over previous
//
#include <hip/hip_runtime.h>
#include <math.h>

#define DIM 256
#define HEADS 8
#define HD 32
// log2(e)/sqrt(32): folded into stored Q so attention uses native exp2
#define QSCALE 0.25504526770295183f

typedef __attribute__((ext_vector_type(8))) short bf16x8;
typedef __attribute__((ext_vector_type(4))) float f32x4;

#if __has_builtin(__builtin_amdgcn_exp2f)
#define EXP2(x) __builtin_amdgcn_exp2f(x)
#else
#define EXP2(x) __expf((x) * 0.6931471805599453f)
#endif

__device__ __forceinline__ unsigned short f2bf(float f) {
  unsigned int u = __float_as_uint(f);
  unsigned int r = u + 0x7fff + ((u >> 16) & 1);   // round-to-nearest-even
  return (unsigned short)(r >> 16);
}
__device__ __forceinline__ float bf2f(unsigned short u) {
  return __uint_as_float(((unsigned int)u) << 16);
}

// MFMA frag layout for a bf16 matrix [R][K] (R%16==0, K%32==0):
//   block id = (r>>4)*(K/32) + (k>>5), 512 shorts per block
//   offset   = ((k&31)>>3)*128 + (r&15)*8 + (k&7)
// GEMM load: base + bid*512 + lane*8  (contiguous 1KB per wave)

// ---------------- prep: avgpools + weight cvts into FRAG layout -----------------
__global__ __launch_bounds__(256) void prep_kernel(const float* __restrict__ x,
    const float* __restrict__ pw_w, const float* __restrict__ fus_w,
    float* __restrict__ xs2, float* __restrict__ xs4,
    unsigned short* __restrict__ Wb, unsigned short* __restrict__ Wf) {
  const int gx = blockIdx.x, t = threadIdx.x;
  if (gx < 1024) {                                  // avgpool s=2 -> 256x32x32
    int id = gx * 256 + t;
    int c = id >> 10, n = id & 1023;
    int y = (n >> 5) << 1, x0 = (n & 31) << 1;
    const float* b = x + c * 4096 + y * 64 + x0;
    xs2[id] = (b[0] + b[1] + b[64] + b[65]) * 0.25f;
  } else if (gx < 1280) {                           // avgpool s=4 -> 256x16x16
    int id = (gx - 1024) * 256 + t;
    int c = id >> 8, n = id & 255;
    int y = (n >> 4) << 2, x0 = (n & 15) << 2;
    const float* b = x + c * 4096 + y * 64 + x0;
    float s = 0.f;
    #pragma unroll
    for (int dy = 0; dy < 4; ++dy)
      #pragma unroll
      for (int dx = 0; dx < 4; ++dx) s += b[dy * 64 + dx];
    xs4[id] = s * 0.0625f;
  } else if (gx < 1424) {                           // pw_w -> Wb frag (3x768x256)
    int lid = (gx - 1280) * 256 + t;
    int fb = lid >> 5, l = lid & 31;                // fb < 1152
    int scale = fb / 384, bs = fb - scale * 384;
    int rtile = bs >> 3, kchunk = bs & 7;
    int r = scale * 768 + rtile * 16 + (l & 7) * 2;
    int k = kchunk * 32 + (l >> 3) * 8;
    const float* s0 = pw_w + (size_t)r * 256 + k;
    float4 u0 = *(const float4*)(s0);
    float4 u1 = *(const float4*)(s0 + 4);
    float4 u2 = *(const float4*)(s0 + 256);
    float4 u3 = *(const float4*)(s0 + 260);
    unsigned short* d = Wb + (size_t)fb * 512 + l * 16;
    ushort4 a0 = {f2bf(u0.x), f2bf(u0.y), f2bf(u0.z), f2bf(u0.w)};
    ushort4 a1 = {f2bf(u1.x), f2bf(u1.y), f2bf(u1.z), f2bf(u1.w)};
    ushort4 a2 = {f2bf(u2.x), f2bf(u2.y), f2bf(u2.z), f2bf(u2.w)};
    ushort4 a3 = {f2bf(u3.x), f2bf(u3.y), f2bf(u3.z), f2bf(u3.w)};
    *(ushort4*)(d)      = a0;
    *(ushort4*)(d + 4)  = a1;
    *(ushort4*)(d + 8)  = a2;
    *(ushort4*)(d + 12) = a3;
  } else {                                          // fus_w -> Wf frag (256x768)
    int lid = (gx - 1424) * 256 + t;
    int fb = lid >> 5, l = lid & 31;                // fb < 384
    int rtile = fb / 24, kchunk = fb - rtile * 24;
    int r = rtile * 16 + (l & 7) * 2;
    int k = kchunk * 32 + (l >> 3) * 8;
    const float* s0 = fus_w + (size_t)r * 768 + k;
    float4 u0 = *(const float4*)(s0);
    float4 u1 = *(const float4*)(s0 + 4);
    float4 u2 = *(const float4*)(s0 + 768);
    float4 u3 = *(const float4*)(s0 + 772);
    unsigned short* d = Wf + (size_t)fb * 512 + l * 16;
    ushort4 a0 = {f2bf(u0.x), f2bf(u0.y), f2bf(u0.z), f2bf(u0.w)};
    ushort4 a1 = {f2bf(u1.x), f2bf(u1.y), f2bf(u1.z), f2bf(u1.w)};
    ushort4 a2 = {f2bf(u2.x), f2bf(u2.y), f2bf(u2.z), f2bf(u2.w)};
    ushort4 a3 = {f2bf(u3.x), f2bf(u3.y), f2bf(u3.z), f2bf(u3.w)};
    *(ushort4*)(d)      = a0;
    *(ushort4*)(d + 4)  = a1;
    *(ushort4*)(d + 8)  = a2;
    *(ushort4*)(d + 12) = a3;
  }
}

// ---------------- fused dwconv(dw+pos): xdwT FRAG layout, posTc [c][Ns] ---------
// 32c x 32n per block, 1 c-position/thread. 1344 blocks.
__global__ __launch_bounds__(256) void dwt_kernel(const float* __restrict__ x,
    const float* __restrict__ xs2, const float* __restrict__ xs4,
    const float* __restrict__ dw_w, const float* __restrict__ dw_b,
    const float* __restrict__ pos_w, const float* __restrict__ pos_b,
    unsigned short* __restrict__ xdwT, unsigned short* __restrict__ posTc) {
  __shared__ __align__(16) unsigned short lds1[32][40];
  int b = blockIdx.x;
  const float* src;
  int lgHs, wo, soff;
  if (b < 1024)      { src = x;   lgHs = 6; wo = 0; soff = 0; }
  else if (b < 1280) { b -= 1024; src = xs2; lgHs = 5; wo = 1; soff = 1048576; }
  else               { b -= 1280; src = xs4; lgHs = 4; wo = 2; soff = 1310720; }
  const int c0 = (b & 7) * 32;
  const int n0 = (b >> 3) * 32;
  const int Hs = 1 << lgHs;
  const int Ns = Hs * Hs;
  const int t = threadIdx.x;
  const int cl = t >> 3;
  const int c = c0 + cl;
  const int nb = (t & 7) * 4;
  const float* w1 = dw_w + wo * 2304 + c * 9;
  const float* w2 = pos_w + wo * 2304 + c * 9;
  const float b1 = dw_b[wo * 256 + c], b2 = pos_b[wo * 256 + c];
  const int gn = n0 + nb;
  const int y = gn >> lgHs, xg = gn & (Hs - 1);
  const float* sc = src + c * Ns;
  float r[3][6];
  #pragma unroll
  for (int ky = 0; ky < 3; ++ky) {
    int yy = y + ky - 1;
    bool rok = (yy >= 0) && (yy < Hs);
    #pragma unroll
    for (int j = 0; j < 6; ++j) {
      int xx = xg - 1 + j;
      r[ky][j] = (rok && xx >= 0 && xx < Hs) ? sc[yy * Hs + xx] : 0.f;
    }
  }
  ushort4 pst;
  unsigned short* ps = (unsigned short*)&pst;
  #pragma unroll
  for (int i = 0; i < 4; ++i) {
    float s1 = b1, s2 = b2;
    #pragma unroll
    for (int ky = 0; ky < 3; ++ky)
      #pragma unroll
      for (int kx = 0; kx < 3; ++kx) {
        float v = r[ky][i + kx];
        s1 += v * w1[ky * 3 + kx];
        s2 += v * w2[ky * 3 + kx];
      }
    lds1[nb + i][cl] = f2bf(s1);
    ps[i] = f2bf(s2);
  }
  *(ushort4*)(posTc + soff + (size_t)c * Ns + gn) = pst;
  __syncthreads();
  if (t < 128) {                                    // 2 frag blocks x 512 shorts
    int blk = t >> 6, l = t & 63;
    size_t bid = (size_t)((n0 >> 4) + blk) * 8 + (c0 >> 5);
    *(bf16x8*)(xdwT + soff + bid * 512 + (size_t)l * 8) =
        *(const bf16x8*)&lds1[blk * 16 + (l & 15)][(l >> 4) * 8];
  }
}

// ---------------- QKV GEMM, frag loads -> frag outputs; posTc coalesced ---------
__global__ __launch_bounds__(256) void gemm_qkv_all(const unsigned short* __restrict__ WbA,
    const unsigned short* __restrict__ xdwTA, const float* __restrict__ biasA,
    const unsigned short* __restrict__ posTA, unsigned short* __restrict__ Qf,
    unsigned short* __restrict__ Kf, unsigned short* __restrict__ Vf) {
  int by = blockIdx.y;
  int Ns, off;
  const unsigned short *Wb, *xdwT, *posT;
  const float* bias;
  if (by < 64) {
    Ns = 4096; off = 0;
    Wb = WbA; bias = biasA;
  } else if (by < 80) {
    Ns = 1024; off = 1048576; by -= 64;
    Wb = WbA + 196608; bias = biasA + 768;
  } else {
    Ns = 256; off = 1310720; by -= 80;
    Wb = WbA + 393216; bias = biasA + 1536;
  }
  xdwT = xdwTA + off; posT = posTA + off;
  const int t = threadIdx.x;
  const int wave = t >> 6, lane = t & 63;
  const int ln = lane & 15, quad = lane >> 4;
  const int o0 = blockIdx.x * 64 + (wave & 1) * 32;
  const int n0 = by * 64 + (wave >> 1) * 32;
  const int at0 = (o0 >> 4) * 8, at1 = at0 + 8;
  const int bt0 = (n0 >> 4) * 8, bt1 = bt0 + 8;
  const bool vblk = blockIdx.x >= 8;
  f32x4 acc[2][2] = {};
  if (!vblk) {
    #pragma unroll
    for (int ks = 0; ks < 8; ++ks) {
      bf16x8 af0 = *(const bf16x8*)(Wb + (size_t)(at0 + ks) * 512 + lane * 8);
      bf16x8 af1 = *(const bf16x8*)(Wb + (size_t)(at1 + ks) * 512 + lane * 8);
      bf16x8 bv0 = *(const bf16x8*)(xdwT + (size_t)(bt0 + ks) * 512 + lane * 8);
      bf16x8 bv1 = *(const bf16x8*)(xdwT + (size_t)(bt1 + ks) * 512 + lane * 8);
      acc[0][0] = __builtin_amdgcn_mfma_f32_16x16x32_bf16(af0, bv0, acc[0][0], 0, 0, 0);
      acc[0][1] = __builtin_amdgcn_mfma_f32_16x16x32_bf16(af0, bv1, acc[0][1], 0, 0, 0);
      acc[1][0] = __builtin_amdgcn_mfma_f32_16x16x32_bf16(af1, bv0, acc[1][0], 0, 0, 0);
      acc[1][1] = __builtin_amdgcn_mfma_f32_16x16x32_bf16(af1, bv1, acc[1][1], 0, 0, 0);
    }
  } else {
    #pragma unroll
    for (int ks = 0; ks < 8; ++ks) {
      bf16x8 af0 = *(const bf16x8*)(Wb + (size_t)(at0 + ks) * 512 + lane * 8);
      bf16x8 af1 = *(const bf16x8*)(Wb + (size_t)(at1 + ks) * 512 + lane * 8);
      bf16x8 bv0 = *(const bf16x8*)(xdwT + (size_t)(bt0 + ks) * 512 + lane * 8);
      bf16x8 bv1 = *(const bf16x8*)(xdwT + (size_t)(bt1 + ks) * 512 + lane * 8);
      // swapped: C^T -> row = n, col = o
      acc[0][0] = __builtin_amdgcn_mfma_f32_16x16x32_bf16(bv0, af0, acc[0][0], 0, 0, 0);
      acc[0][1] = __builtin_amdgcn_mfma_f32_16x16x32_bf16(bv0, af1, acc[0][1], 0, 0, 0);
      acc[1][0] = __builtin_amdgcn_mfma_f32_16x16x32_bf16(bv1, af0, acc[1][0], 0, 0, 0);
      acc[1][1] = __builtin_amdgcn_mfma_f32_16x16x32_bf16(bv1, af1, acc[1][1], 0, 0, 0);
    }
  }
  if (!vblk) {                                      // q or k: rows=o, cols=n
    const int cat = blockIdx.x >> 2;                // 0=q, 1=k
    #pragma unroll
    for (int mt = 0; mt < 2; ++mt) {
      int ot = o0 + mt * 16 + quad * 4;
      float bs0 = bias[ot], bs1 = bias[ot + 1], bs2 = bias[ot + 2], bs3 = bias[ot + 3];
      int cb = ot & 255;
      #pragma unroll
      for (int nt = 0; nt < 2; ++nt) {
        int nn = n0 + nt * 16 + ln;
        f32x4 v = acc[mt][nt];
        const unsigned short* pp = posT + (size_t)cb * Ns + nn;
        v.x += bs0 + bf2f(pp[0]);
        v.y += bs1 + bf2f(pp[Ns]);
        v.z += bs2 + bf2f(pp[2 * Ns]);
        v.w += bs3 + bf2f(pp[3 * Ns]);
        if (cat == 0) { v.x *= QSCALE; v.y *= QSCALE; v.z *= QSCALE; v.w *= QSCALE; }
        ushort4 st;
        st.x = f2bf(v.x); st.y = f2bf(v.y); st.z = f2bf(v.z); st.w = f2bf(v.w);
        int hh = cb >> 5, d = cb & 31;
        unsigned short* dst = (cat == 0 ? Qf : Kf) + off;
        size_t a = ((size_t)(hh * (Ns >> 4) + (nn >> 4)) * 64 + (d >> 3) * 16 + (nn & 15)) * 8
                   + (d & 7);
        *(ushort4*)(dst + a) = st;
      }
    }
  } else {                                          // v: rows=n, cols=o
    #pragma unroll
    for (int a = 0; a < 2; ++a) {
      int nbase = n0 + a * 16 + quad * 4;
      #pragma unroll
      for (int bb = 0; bb < 2; ++bb) {
        int o = o0 + bb * 16 + ln;
        int c = o - 512;
        int hh = c >> 5, d = c & 31;
        int dt = d >> 4, dl = d & 15;
        float bs = bias[o];
        f32x4 v = acc[a][bb];
        ushort4 st;
        st.x = f2bf(v.x + bs); st.y = f2bf(v.y + bs);
        st.z = f2bf(v.z + bs); st.w = f2bf(v.w + bs);
        size_t adr = ((((size_t)hh * (Ns >> 5) + (nbase >> 5)) * 2 + dt) * 64
                      + ((nbase & 31) >> 3) * 16 + dl) * 8 + (nbase & 7);
        *(ushort4*)(Vf + off + adr) = st;
      }
    }
  }
}

// ---------------- attention: frag loads, 4 splits/scale, interleaved exp/PV -----
// z 0..3: s1 splits (lgMs=10); z 4..7: s2 (x<8, lgMs=8); z 8..11: s4 (x<2, lgMs=6).
__global__ __launch_bounds__(256) void attn_all_kernel(
    const unsigned short* __restrict__ Qf, const unsigned short* __restrict__ Kf,
    const unsigned short* __restrict__ Vf,
    unsigned short* __restrict__ accp1, unsigned short* __restrict__ p2,
    unsigned short* __restrict__ p4, float* __restrict__ ls1,
    float* __restrict__ ls2, float* __restrict__ ls4) {
  __shared__ unsigned short pt_lds[4 * 32 * 72];    // wave-private P^T [n][m], pad 72
  const int z = blockIdx.z;
  unsigned short* accp;
  float* lsump;
  int Ns, lgMs, sp, off;
  if (z < 4) {
    accp = accp1; lsump = ls1; Ns = 4096; lgMs = 10; sp = z; off = 0;
  } else if (z < 8) {
    if (blockIdx.x >= 8) return;
    accp = p2; lsump = ls2; Ns = 1024; lgMs = 8; sp = z - 4; off = 1048576;
  } else {
    if (blockIdx.x >= 2) return;
    accp = p4; lsump = ls4; Ns = 256; lgMs = 6; sp = z - 8; off = 1310720;
  }
  const int t = threadIdx.x;
  const int wave = t >> 6, lane = t & 63;
  const int ln = lane & 15, quad = lane >> 4;
  const int h = blockIdx.y;
  const int n0 = blockIdx.x * 128 + wave * 32;
  const unsigned short* qp = Qf + off
      + ((size_t)(h * (Ns >> 4) + (n0 >> 4)) * 64 + lane) * 8;
  bf16x8 qf0 = *(const bf16x8*)(qp);
  bf16x8 qf1 = *(const bf16x8*)(qp + 512);
  unsigned short* ptw = pt_lds + wave * (32 * 72);
  f32x4 acc[2][2] = {};
  f32x4 acc_l0 = {0.f, 0.f, 0.f, 0.f}, acc_l1 = {0.f, 0.f, 0.f, 0.f};
  const f32x4 zero = {0.f, 0.f, 0.f, 0.f};
  const short kOne = (short)0x3F80;                 // bf16 1.0
  const bf16x8 onesf = {kOne, kOne, kOne, kOne, kOne, kOne, kOne, kOne};
  const int m0s = sp << lgMs;
  const int nch = 1 << (lgMs - 6);
  const unsigned short* kp = Kf + off
      + ((size_t)(h * (Ns >> 4) + (m0s >> 4)) * 64 + lane) * 8;
  const unsigned short* vp = Vf + off
      + (((size_t)h * (Ns >> 5) + (m0s >> 5)) * 128 + lane) * 8;
  for (int ch = 0; ch < nch; ++ch) {
    const unsigned short* kc = kp + ch * 2048;
    const unsigned short* vc = vp + ch * 2048;
    bf16x8 kf0 = *(const bf16x8*)(kc);
    bf16x8 kf1 = *(const bf16x8*)(kc + 512);
    bf16x8 kf2 = *(const bf16x8*)(kc + 1024);
    bf16x8 kf3 = *(const bf16x8*)(kc + 1536);
    bf16x8 vf00 = *(const bf16x8*)(vc);          // ks0, dt0
    bf16x8 vf10 = *(const bf16x8*)(vc + 512);    // ks0, dt1
    bf16x8 vf01 = *(const bf16x8*)(vc + 1024);   // ks1, dt0
    bf16x8 vf11 = *(const bf16x8*)(vc + 1536);   // ks1, dt1
    f32x4 s[4][2];
    s[0][0] = __builtin_amdgcn_mfma_f32_16x16x32_bf16(kf0, qf0, zero, 0, 0, 0);
    s[0][1] = __builtin_amdgcn_mfma_f32_16x16x32_bf16(kf0, qf1, zero, 0, 0, 0);
    s[1][0] = __builtin_amdgcn_mfma_f32_16x16x32_bf16(kf1, qf0, zero, 0, 0, 0);
    s[1][1] = __builtin_amdgcn_mfma_f32_16x16x32_bf16(kf1, qf1, zero, 0, 0, 0);
    s[2][0] = __builtin_amdgcn_mfma_f32_16x16x32_bf16(kf2, qf0, zero, 0, 0, 0);
    s[2][1] = __builtin_amdgcn_mfma_f32_16x16x32_bf16(kf2, qf1, zero, 0, 0, 0);
    s[3][0] = __builtin_amdgcn_mfma_f32_16x16x32_bf16(kf3, qf0, zero, 0, 0, 0);
    s[3][1] = __builtin_amdgcn_mfma_f32_16x16x32_bf16(kf3, qf1, zero, 0, 0, 0);
    // exp+pack mt0,mt1 (cols 0..31 of ptw)
    #pragma unroll
    for (int mt = 0; mt < 2; ++mt) {
      #pragma unroll
      for (int nt = 0; nt < 2; ++nt) {
        float e0 = EXP2(s[mt][nt].x);
        float e1 = EXP2(s[mt][nt].y);
        float e2 = EXP2(s[mt][nt].z);
        float e3 = EXP2(s[mt][nt].w);
        uint2 pk;
        pk.x = __builtin_amdgcn_perm(__float_as_uint(e1), __float_as_uint(e0), 0x07060302);
        pk.y = __builtin_amdgcn_perm(__float_as_uint(e3), __float_as_uint(e2), 0x07060302);
        *(uint2*)&ptw[(nt * 16 + ln) * 72 + mt * 16 + quad * 4] = pk;
      }
    }
    // PV ks0 — its MFMAs execute while the mt2/mt3 exp VALU below issues
    {
      bf16x8 pf0 = *(const bf16x8*)&ptw[ln * 72 + quad * 8];
      bf16x8 pf1 = *(const bf16x8*)&ptw[(16 + ln) * 72 + quad * 8];
      acc[0][0] = __builtin_amdgcn_mfma_f32_16x16x32_bf16(vf00, pf0, acc[0][0], 0, 0, 0);
      acc[0][1] = __builtin_amdgcn_mfma_f32_16x16x32_bf16(vf00, pf1, acc[0][1], 0, 0, 0);
      acc[1][0] = __builtin_amdgcn_mfma_f32_16x16x32_bf16(vf10, pf0, acc[1][0], 0, 0, 0);
      acc[1][1] = __builtin_amdgcn_mfma_f32_16x16x32_bf16(vf10, pf1, acc[1][1], 0, 0, 0);
      acc_l0 = __builtin_amdgcn_mfma_f32_16x16x32_bf16(onesf, pf0, acc_l0, 0, 0, 0);
      acc_l1 = __builtin_amdgcn_mfma_f32_16x16x32_bf16(onesf, pf1, acc_l1, 0, 0, 0);
    }
    // exp+pack mt2,mt3 (cols 32..63)
    #pragma unroll
    for (int mt = 2; mt < 4; ++mt) {
      #pragma unroll
      for (int nt = 0; nt < 2; ++nt) {
        float e0 = EXP2(s[mt][nt].x);
        float e1 = EXP2(s[mt][nt].y);
        float e2 = EXP2(s[mt][nt].z);
        float e3 = EXP2(s[mt][nt].w);
        uint2 pk;
        pk.x = __builtin_amdgcn_perm(__float_as_uint(e1), __float_as_uint(e0), 0x07060302);
        pk.y = __builtin_amdgcn_perm(__float_as_uint(e3), __float_as_uint(e2), 0x07060302);
        *(uint2*)&ptw[(nt * 16 + ln) * 72 + mt * 16 + quad * 4] = pk;
      }
    }
    // PV ks1
    {
      bf16x8 pf0 = *(const bf16x8*)&ptw[ln * 72 + 32 + quad * 8];
      bf16x8 pf1 = *(const bf16x8*)&ptw[(16 + ln) * 72 + 32 + quad * 8];
      acc[0][0] = __builtin_amdgcn_mfma_f32_16x16x32_bf16(vf01, pf0, acc[0][0], 0, 0, 0);
      acc[0][1] = __builtin_amdgcn_mfma_f32_16x16x32_bf16(vf01, pf1, acc[0][1], 0, 0, 0);
      acc[1][0] = __builtin_amdgcn_mfma_f32_16x16x32_bf16(vf11, pf0, acc[1][0], 0, 0, 0);
      acc[1][1] = __builtin_amdgcn_mfma_f32_16x16x32_bf16(vf11, pf1, acc[1][1], 0, 0, 0);
      acc_l0 = __builtin_amdgcn_mfma_f32_16x16x32_bf16(onesf, pf0, acc_l0, 0, 0, 0);
      acc_l1 = __builtin_amdgcn_mfma_f32_16x16x32_bf16(onesf, pf1, acc_l1, 0, 0, 0);
    }
  }
  unsigned short* ap = accp + ((size_t)sp * 256 + h * 32) * Ns;
  #pragma unroll
  for (int dt = 0; dt < 2; ++dt) {
    #pragma unroll
    for (int r = 0; r < 4; ++r) {
      int cl = dt * 16 + quad * 4 + r;
      ap[(size_t)cl * Ns + n0 + ln]      = f2bf(((const float*)&acc[dt][0])[r]);
      ap[(size_t)cl * Ns + n0 + 16 + ln] = f2bf(((const float*)&acc[dt][1])[r]);
    }
  }
  if (lane < 16) {
    float* lp = lsump + ((size_t)sp * 8 + h) * Ns + n0;
    lp[lane]      = acc_l0.x;                       // all rows of ones-MFMA equal lsum_n
    lp[16 + lane] = acc_l1.x;
  }
}

// ---------------- combine s2 (4 splits) + s4 (4 splits) in one launch -----------
__global__ __launch_bounds__(256) void combine24_kernel(const unsigned short* __restrict__ p2,
    const float* __restrict__ ls2, const unsigned short* __restrict__ p4,
    const float* __restrict__ ls4, float* __restrict__ out2, float* __restrict__ out4) {
  int id = blockIdx.x * 256 + threadIdx.x;
  if (id < 262144) {                                // s2: 256 x 1024
    int n = id & 1023, h = id >> 15;
    float v = 0.f, d = 0.f;
    #pragma unroll
    for (int sp = 0; sp < 4; ++sp) {
      v += bf2f(p2[sp * 262144 + id]);
      d += ls2[sp * 8192 + h * 1024 + n];
    }
    out2[id] = v / d;
  } else {                                          // s4: 256 x 256
    int idl = id - 262144;
    int n = idl & 255, h = idl >> 13;
    float v = 0.f, d = 0.f;
    #pragma unroll
    for (int sp = 0; sp < 4; ++sp) {
      v += bf2f(p4[sp * 65536 + idl]);
      d += ls4[sp * 2048 + h * 256 + n];
    }
    out4[idl] = v / d;
  }
}

// ---------------- build catT in FRAG layout (R=4096 rows n, K=768 cols c) -------
__global__ __launch_bounds__(256) void build_catT_kernel(const unsigned short* __restrict__ accp,
    const float* __restrict__ lsum1, const float* __restrict__ out2,
    const float* __restrict__ out4, unsigned short* __restrict__ catT) {
  __shared__ unsigned short lds[64][72];
  const int t = threadIdx.x;
  const int n0 = blockIdx.x * 64;
  const int by = blockIdx.y;
  const int c0 = by * 64;
  if (by < 4) {
    #pragma unroll
    for (int p = 0; p < 4; ++p) {
      int ct = p * 16 + (t >> 4);
      int c = c0 + ct;
      int h = c >> 5;
      int nn = (t & 15) * 4;
      float vs[4] = {0.f, 0.f, 0.f, 0.f};
      float ds[4] = {0.f, 0.f, 0.f, 0.f};
      #pragma unroll
      for (int sp = 0; sp < 4; ++sp) {
        ushort4 a = *(const ushort4*)(accp + (size_t)sp * 1048576 + (size_t)c * 4096 + n0 + nn);
        vs[0] += bf2f(a.x); vs[1] += bf2f(a.y); vs[2] += bf2f(a.z); vs[3] += bf2f(a.w);
        float4 dd = *(const float4*)(lsum1 + (size_t)sp * 32768 + (size_t)h * 4096 + n0 + nn);
        ds[0] += dd.x; ds[1] += dd.y; ds[2] += dd.z; ds[3] += dd.w;
      }
      lds[nn + 0][ct] = f2bf(vs[0] / ds[0]);
      lds[nn + 1][ct] = f2bf(vs[1] / ds[1]);
      lds[nn + 2][ct] = f2bf(vs[2] / ds[2]);
      lds[nn + 3][ct] = f2bf(vs[3] / ds[3]);
    }
  } else {
    const bool s2 = by < 8;
    const float* src = s2 ? out2 : out4;
    const int Hs = s2 ? 32 : 16;
    const int coff = s2 ? 256 : 512;
    const float sc = (float)Hs / 64.0f;
    #pragma unroll
    for (int p = 0; p < 4; ++p) {
      int ct = p * 16 + (t >> 4);
      const float* s = src + (size_t)(c0 - coff + ct) * Hs * Hs;
      int nn = (t & 15) * 4;
      #pragma unroll
      for (int i = 0; i < 4; ++i) {
        int n = n0 + nn + i;
        int y = n >> 6, x = n & 63;
        float fy = ((float)y + 0.5f) * sc - 0.5f;
        float fx = ((float)x + 0.5f) * sc - 0.5f;
        float fy0 = floorf(fy), fx0 = floorf(fx);
        int y0 = (int)fy0, x0 = (int)fx0;
        float ty = fy - fy0, tx = fx - fx0;
        int y0c = min(max(y0, 0), Hs - 1), y1c = min(max(y0 + 1, 0), Hs - 1);
        int x0c = min(max(x0, 0), Hs - 1), x1c = min(max(x0 + 1, 0), Hs - 1);
        float v00 = s[y0c * Hs + x0c], v01 = s[y0c * Hs + x1c];
        float v10 = s[y1c * Hs + x0c], v11 = s[y1c * Hs + x1c];
        float v0 = v00 + (v01 - v00) * tx;
        float v1 = v10 + (v11 - v10) * tx;
        lds[nn + i][ct] = f2bf(v0 + (v1 - v0) * ty);
      }
    }
  }
  __syncthreads();
  // frag write: 8 blocks (4 n-tiles x 2 c-chunks) x 512 shorts, 32 threads each
  int blk = t >> 5, l = t & 31;
  int ntile = blk >> 1, cchunk = blk & 1;
  int koct = l >> 3, r1 = (l & 7) * 2;
  size_t bid = (size_t)((n0 >> 4) + ntile) * 24 + (c0 >> 5) + cchunk;
  unsigned short* dst = catT + bid * 512 + (size_t)l * 16;
  *(bf16x8*)(dst)     = *(const bf16x8*)&lds[ntile * 16 + r1][cchunk * 32 + koct * 8];
  *(bf16x8*)(dst + 8) = *(const bf16x8*)&lds[ntile * 16 + r1 + 1][cchunk * 32 + koct * 8];
}

// ---------------- fusion GEMM: full K=768, partial unroll, direct out + bias ----
__global__ __launch_bounds__(256) void gemm_fus_mfma(const unsigned short* __restrict__ Wf,
    const unsigned short* __restrict__ catT, const float* __restrict__ bias,
    float* __restrict__ out) {
  const int t = threadIdx.x;
  const int wave = t >> 6, lane = t & 63;
  const int ln = lane & 15, quad = lane >> 4;
  const int o0 = blockIdx.x * 64 + (wave & 1) * 32;
  const int n0 = blockIdx.y * 64 + (wave >> 1) * 32;
  const int at0 = (o0 >> 4) * 24, at1 = at0 + 24;
  const int bt0 = (n0 >> 4) * 24, bt1 = bt0 + 24;
  f32x4 acc[2][2] = {};                             // [n-tile][o-tile] (C^T)
  #pragma unroll 4
  for (int ks = 0; ks < 24; ++ks) {
    bf16x8 af0 = *(const bf16x8*)(Wf + (size_t)(at0 + ks) * 512 + lane * 8);
    bf16x8 af1 = *(const bf16x8*)(Wf + (size_t)(at1 + ks) * 512 + lane * 8);
    bf16x8 bv0 = *(const bf16x8*)(catT + (size_t)(bt0 + ks) * 512 + lane * 8);
    bf16x8 bv1 = *(const bf16x8*)(catT + (size_t)(bt1 + ks) * 512 + lane * 8);
    acc[0][0] = __builtin_amdgcn_mfma_f32_16x16x32_bf16(bv0, af0, acc[0][0], 0, 0, 0);
    acc[0][1] = __builtin_amdgcn_mfma_f32_16x16x32_bf16(bv0, af1, acc[0][1], 0, 0, 0);
    acc[1][0] = __builtin_amdgcn_mfma_f32_16x16x32_bf16(bv1, af0, acc[1][0], 0, 0, 0);
    acc[1][1] = __builtin_amdgcn_mfma_f32_16x16x32_bf16(bv1, af1, acc[1][1], 0, 0, 0);
  }
  #pragma unroll
  for (int a = 0; a < 2; ++a) {
    int nbase = n0 + a * 16 + quad * 4;
    #pragma unroll
    for (int bb = 0; bb < 2; ++bb) {
      int o = o0 + bb * 16 + ln;
      float bs = bias[o];
      float4 st;
      st.x = acc[a][bb].x + bs; st.y = acc[a][bb].y + bs;
      st.z = acc[a][bb].z + bs; st.w = acc[a][bb].w + bs;
      *(float4*)(out + (size_t)o * 4096 + nbase) = st;
    }
  }
}

extern "C" void kernel_launch(void* const* d_in, const int* in_sizes, int n_in,
                              void* d_out, int out_size, void* d_ws, size_t ws_size,
                              hipStream_t stream) {
  const float* x     = (const float*)d_in[0];
  const float* dw_w  = (const float*)d_in[1];
  const float* dw_b  = (const float*)d_in[2];
  const float* pw_w  = (const float*)d_in[3];
  const float* pw_b  = (const float*)d_in[4];
  const float* pos_w = (const float*)d_in[5];
  const float* pos_b = (const float*)d_in[6];
  const float* fus_w = (const float*)d_in[7];
  const float* fus_b = (const float*)d_in[8];
  float* out = (float*)d_out;
  float* ws = (float*)d_ws;

  // ws layout (floats), total 12,058,624 fl = 46.0 MB (aliasing noted inline)
  float* scratch = ws;                       // 1,376,256  [attn s2/s4 bf16 partials]
  float* posF   = ws + 1376256;              // 1,376,256  [lsum1/2/4 + out2/out4]
  float* accpF  = ws + 2752512;              // 4,194,304  [xs2/xs4 early; s1 bf16 partials]
  unsigned short* xdwT = (unsigned short*)(ws + 6946816);   // 1,376,256 us (frag)
  unsigned short* posTc = (unsigned short*)(ws + 7634944);  // 1,376,256 us ([c][Ns])
  unsigned short* Qf   = (unsigned short*)(ws + 8323072);   // 1,376,256 us
  unsigned short* Kf   = Qf + 1376256;                      // 1,376,256 us
  unsigned short* Vf   = (unsigned short*)(ws + 9699328);   // 1,376,256 us
  unsigned short* catT = (unsigned short*)(ws + 10387456);  // 3,145,728 us [Wb early]
  unsigned short* Wf   = (unsigned short*)(ws + 11960320);  //   196,608 us

  float* xs2 = accpF;                        // dead before attn-s1 writes accp
  float* xs4 = accpF + 262144;
  unsigned short* Wb = catT;                 // dead before build_catT writes catT
  unsigned short* accp = (unsigned short*)accpF;            // 4,194,304 us (4 splits)
  float* lsump1 = posF;                      // 131,072 (4sp x 8h x 4096)
  float* lsump2 = posF + 262144;             // 32,768
  float* lsump4 = posF + 327680;             // 8,192
  float* out2   = posF + 335872;             // 262,144
  float* out4   = posF + 598016;             // 65,536
  unsigned short* p2 = (unsigned short*)scratch;            // 1,048,576 us (4 splits)
  unsigned short* p4 = (unsigned short*)scratch + 2097152;  //   262,144 us (4 splits)

  prep_kernel<<<1472, 256, 0, stream>>>(x, pw_w, fus_w, xs2, xs4, Wb, Wf);
  dwt_kernel<<<1344, 256, 0, stream>>>(x, xs2, xs4, dw_w, dw_b, pos_w, pos_b, xdwT, posTc);
  gemm_qkv_all<<<dim3(12, 84), 256, 0, stream>>>(Wb, xdwT, pw_b, posTc, Qf, Kf, Vf);

  attn_all_kernel<<<dim3(32, 8, 12), 256, 0, stream>>>(Qf, Kf, Vf, accp, p2, p4,
                                                       lsump1, lsump2, lsump4);
  combine24_kernel<<<1280, 256, 0, stream>>>(p2, lsump2, p4, lsump4, out2, out4);

  build_catT_kernel<<<dim3(64, 12), 256, 0, stream>>>(accp, lsump1, out2, out4, catT);
  gemm_fus_mfma<<<dim3(4, 64), 256, 0, stream>>>(Wf, catT, fus_b, out);
}